// Round 1
// baseline (463.273 us; speedup 1.0000x reference)
//
#include <hip/hip_runtime.h>
#include <hip/hip_bf16.h>
#include <math.h>

constexpr int SEQ    = 2048;
constexpr int NH     = 16;
constexpr int HEAVY  = 204;   // int(0.1*2048)
constexpr int RECENT = 204;   // int(0.1*2048)
constexpr float SCALE = 0.08838834764831845f; // 128^-0.5

typedef _Float16 half8 __attribute__((ext_vector_type(8)));
typedef float f32x4 __attribute__((ext_vector_type(4)));

// ---------- f32 -> f16 convert ----------
__global__ void cvt_h(const float* __restrict__ src, _Float16* __restrict__ dst, int n) {
  int i = (blockIdx.x * 256 + threadIdx.x) * 4;
  if (i + 3 < n) {
    float4 v = *(const float4*)(src + i);
    dst[i] = (_Float16)v.x; dst[i+1] = (_Float16)v.y;
    dst[i+2] = (_Float16)v.z; dst[i+3] = (_Float16)v.w;
  } else {
    for (int u = i; u < n; ++u) dst[u] = (_Float16)src[u];
  }
}

// ---------- transpose + convert: W f32 [K][N] -> WT f16 [N][K] ----------
__global__ __launch_bounds__(256) void transpose_h(
    const float* __restrict__ W, _Float16* __restrict__ WT, int K, int N) {
  __shared__ float T[64][65];
  int c = threadIdx.x & 63, rq = threadIdx.x >> 6;
  int n0 = blockIdx.x * 64, k0 = blockIdx.y * 64;
#pragma unroll
  for (int u = 0; u < 16; ++u) {
    int r = rq * 16 + u;
    T[r][c] = W[(size_t)(k0 + r) * N + n0 + c];
  }
  __syncthreads();
#pragma unroll
  for (int u = 0; u < 16; ++u) {
    int r = rq * 16 + u;
    WT[(size_t)(n0 + r) * K + k0 + c] = (_Float16)T[c][r];
  }
}

// ---------- concat bias [bq|bk|bv] -> 3072 floats ----------
__global__ void concat_bias(const float* __restrict__ bq, const float* __restrict__ bk,
                            const float* __restrict__ bv, float* __restrict__ b) {
  int i = blockIdx.x * 256 + threadIdx.x;
  if (i < 2048) b[i] = bq[i];
  else if (i < 2560) b[i] = bk[i - 2048];
  else if (i < 3072) b[i] = bv[i - 2560];
}

// ---------- MFMA f16 GEMM with split-K (gridDim.z): C pre-zeroed when z>1 ----------
__global__ __launch_bounds__(256) void gemm_h(
    const _Float16* __restrict__ A, const _Float16* __restrict__ BT,
    const float* __restrict__ bias, float* __restrict__ C,
    int M, int N, int K)
{
  __shared__ _Float16 As[128][40];
  __shared__ _Float16 Bs[128][40];
  int tid = threadIdx.x;
  int lane = tid & 63, wave = tid >> 6;
  int wm = (wave & 1) * 64, wn = (wave >> 1) * 64;
  int m0 = blockIdx.y * 128, n0 = blockIdx.x * 128;
  int kz = blockIdx.z, nz = gridDim.z;
  int kchunk = K / nz;
  int kbeg = kz * kchunk, kend = kbeg + kchunk;

  f32x4 acc[4][4] = {};

  int srow = tid >> 2;
  int scol = (tid & 3) * 8;
  int mq = lane & 15, quad = lane >> 4;

  for (int k0 = kbeg; k0 < kend; k0 += 32) {
    *(half8*)&As[srow][scol]      = *(const half8*)(A  + (size_t)(m0 + srow) * K + k0 + scol);
    *(half8*)&As[srow + 64][scol] = *(const half8*)(A  + (size_t)(m0 + srow + 64) * K + k0 + scol);
    *(half8*)&Bs[srow][scol]      = *(const half8*)(BT + (size_t)(n0 + srow) * K + k0 + scol);
    *(half8*)&Bs[srow + 64][scol] = *(const half8*)(BT + (size_t)(n0 + srow + 64) * K + k0 + scol);
    __syncthreads();
    half8 af[4], bf[4];
#pragma unroll
    for (int t4 = 0; t4 < 4; ++t4) {
      af[t4] = *(const half8*)&As[wm + t4 * 16 + mq][quad * 8];
      bf[t4] = *(const half8*)&Bs[wn + t4 * 16 + mq][quad * 8];
    }
#pragma unroll
    for (int mt = 0; mt < 4; ++mt)
#pragma unroll
      for (int nt = 0; nt < 4; ++nt)
        acc[mt][nt] = __builtin_amdgcn_mfma_f32_16x16x32_f16(af[mt], bf[nt], acc[mt][nt], 0, 0, 0);
    __syncthreads();
  }

#pragma unroll
  for (int mt = 0; mt < 4; ++mt)
#pragma unroll
    for (int nt = 0; nt < 4; ++nt) {
      int n = n0 + wn + nt * 16 + mq;
      float bb = bias ? bias[n] : 0.f;
      float bbz = (kz == 0) ? bb : 0.f;
#pragma unroll
      for (int r = 0; r < 4; ++r) {
        int m = m0 + wm + mt * 16 + quad * 4 + r;
        if (nz == 1)
          C[(size_t)m * N + n] = acc[mt][nt][r] + bb;
        else
          unsafeAtomicAdd(&C[(size_t)m * N + n], acc[mt][nt][r] + bbz);
      }
    }
}

// ---------- postproc: qkv f32 [s][3072] -> RoPE'd qh/kh + vh (all f16) ----------
__global__ void postproc(const float* __restrict__ qkv, const float* __restrict__ cosb,
                         const float* __restrict__ sinb, _Float16* __restrict__ qh,
                         _Float16* __restrict__ kh, _Float16* __restrict__ vh) {
  int idx = blockIdx.x * 256 + threadIdx.x;
  const int NQ = SEQ * 16 * 64, NK = SEQ * 4 * 64, NV = SEQ * 4 * 128;
  if (idx < NQ) {
    int d = idx & 63; int rest = idx >> 6; int h = rest & 15; int s = rest >> 4;
    const float* p = qkv + (size_t)s * 3072 + h * 128;
    float x1 = p[d], x2 = p[d + 64];
    float c1 = cosb[(size_t)s * 128 + d], c2 = cosb[(size_t)s * 128 + d + 64];
    float s1 = sinb[(size_t)s * 128 + d], s2 = sinb[(size_t)s * 128 + d + 64];
    qh[(size_t)s * 2048 + h * 128 + d]      = (_Float16)(x1 * c1 - x2 * s1);
    qh[(size_t)s * 2048 + h * 128 + d + 64] = (_Float16)(x2 * c2 + x1 * s2);
  } else if (idx < NQ + NK) {
    int r = idx - NQ;
    int d = r & 63; int rest = r >> 6; int h = rest & 3; int s = rest >> 2;
    const float* p = qkv + (size_t)s * 3072 + 2048 + h * 128;
    float x1 = p[d], x2 = p[d + 64];
    float c1 = cosb[(size_t)s * 128 + d], c2 = cosb[(size_t)s * 128 + d + 64];
    float s1 = sinb[(size_t)s * 128 + d], s2 = sinb[(size_t)s * 128 + d + 64];
    kh[(size_t)s * 512 + h * 128 + d]      = (_Float16)(x1 * c1 - x2 * s1);
    kh[(size_t)s * 512 + h * 128 + d + 64] = (_Float16)(x2 * c2 + x1 * s2);
  } else if (idx < NQ + NK + NV) {
    int r = idx - NQ - NK;
    int d = r & 127; int rest = r >> 7; int h = rest & 3; int s = rest >> 2;
    vh[(size_t)s * 512 + h * 128 + d] = (_Float16)qkv[(size_t)s * 3072 + 2560 + h * 128 + d];
  }
}

// ---------- S1: flash row stats (m_i, l_i), Q in registers, j-split ----------
__global__ __launch_bounds__(256) void flashstats(
    const _Float16* __restrict__ qh, const _Float16* __restrict__ kh,
    float* __restrict__ rowmP, float* __restrict__ rowlP)
{
  int sp = blockIdx.x;                    // j-split 0/1
  int ib = blockIdx.y;
  int i0 = ib * 128, h = blockIdx.z, kvh = h >> 2;
  __shared__ _Float16 Ks[128][136];
  int tid = threadIdx.x, lane = tid & 63, wave = tid >> 6;
  int mq = lane & 15, quad = lane >> 4;
  int wm = wave * 32;

  // Q fragments held in registers (per-lane MFMA A-fragment, loaded once)
  half8 aq[2][4];
#pragma unroll
  for (int rt = 0; rt < 2; ++rt)
#pragma unroll
    for (int ks = 0; ks < 4; ++ks)
      aq[rt][ks] = *(const half8*)(qh + (size_t)(i0 + wm + rt * 16 + mq) * 2048 + h * 128 + ks * 32 + quad * 8);

  float runm[2][4], runl[2][4];
#pragma unroll
  for (int rt = 0; rt < 2; ++rt)
#pragma unroll
    for (int r = 0; r < 4; ++r) { runm[rt][r] = -INFINITY; runl[rt][r] = 0.f; }

  int nblk = ib + 1;
  int jb_lo = sp ? (nblk >> 1) : 0;
  int jb_hi = sp ? nblk : (nblk >> 1);
  for (int jb = jb_lo; jb < jb_hi; ++jb) {
    int j0 = jb * 128;
    __syncthreads();
#pragma unroll
    for (int u = 0; u < 8; ++u) {
      int unit = u * 256 + tid;
      int r = unit >> 4, c8 = (unit & 15) * 8;
      *(half8*)&Ks[r][c8] = *(const half8*)(kh + (size_t)(j0 + r) * 512 + kvh * 128 + c8);
    }
    __syncthreads();

    f32x4 acc[2][8] = {};
#pragma unroll
    for (int ks = 0; ks < 4; ++ks) {
      half8 bf[8];
#pragma unroll
      for (int ct = 0; ct < 8; ++ct) bf[ct] = *(const half8*)&Ks[ct * 16 + mq][ks * 32 + quad * 8];
#pragma unroll
      for (int rt = 0; rt < 2; ++rt)
#pragma unroll
        for (int ct = 0; ct < 8; ++ct)
          acc[rt][ct] = __builtin_amdgcn_mfma_f32_16x16x32_f16(aq[rt][ks], bf[ct], acc[rt][ct], 0, 0, 0);
    }

#pragma unroll
    for (int rt = 0; rt < 2; ++rt) {
      int rbase = i0 + wm + rt * 16 + quad * 4;
#pragma unroll
      for (int ct = 0; ct < 8; ++ct) {
        int j = j0 + ct * 16 + mq;
#pragma unroll
        for (int r = 0; r < 4; ++r) {
          float s = acc[rt][ct][r] * SCALE;
          if (j > rbase + r) s = -INFINITY;
          acc[rt][ct][r] = s;
        }
      }
#pragma unroll
      for (int r = 0; r < 4; ++r) {
        float v = acc[rt][0][r];
#pragma unroll
        for (int ct = 1; ct < 8; ++ct) v = fmaxf(v, acc[rt][ct][r]);
        for (int off = 1; off < 16; off <<= 1) v = fmaxf(v, __shfl_xor(v, off, 64));
        float nm = fmaxf(runm[rt][r], v);
        float alpha = (runm[rt][r] == -INFINITY) ? 0.f : __expf(runm[rt][r] - nm);
        float ps = 0.f;
#pragma unroll
        for (int ct = 0; ct < 8; ++ct) ps += __expf(acc[rt][ct][r] - nm);
        for (int off = 1; off < 16; off <<= 1) ps += __shfl_xor(ps, off, 64);
        runl[rt][r] = runl[rt][r] * alpha + ps;
        runm[rt][r] = nm;
      }
    }
  }
  if (mq == 0) {
#pragma unroll
    for (int rt = 0; rt < 2; ++rt)
#pragma unroll
      for (int r = 0; r < 4; ++r) {
        int i = i0 + wm + rt * 16 + quad * 4 + r;
        rowmP[sp * (NH * SEQ) + h * SEQ + i] = runm[rt][r];
        rowlP[sp * (NH * SEQ) + h * SEQ + i] = runl[rt][r];
      }
  }
}

// ---------- merge split row stats ----------
__global__ void mergestats(const float* __restrict__ rowmP, const float* __restrict__ rowlP,
                           float* __restrict__ rowm, float* __restrict__ rowl) {
  int i = blockIdx.x * 256 + threadIdx.x;
  if (i < NH * SEQ) {
    float m0 = rowmP[i], m1 = rowmP[NH * SEQ + i];
    float l0 = rowlP[i], l1 = rowlP[NH * SEQ + i];
    float m = fmaxf(m0, m1);
    float l = 0.f;
    if (l0 > 0.f) l += l0 * __expf(m0 - m);
    if (l1 > 0.f) l += l1 * __expf(m1 - m);
    rowm[i] = m; rowl[i] = l;
  }
}

// ---------- S2: colsum[h][j] = sum_i exp(s_ij - m_i)/l_i, Q streamed from global, i-split ----------
__global__ __launch_bounds__(256) void flashcolsum(
    const _Float16* __restrict__ qh, const _Float16* __restrict__ kh,
    const float* __restrict__ rowm, const float* __restrict__ rowl,
    float* __restrict__ colsumP)
{
  int sp = blockIdx.x;                    // i-split 0/1
  int jb = blockIdx.y;
  int j0 = jb * 128, h = blockIdx.z, kvh = h >> 2;
  __shared__ _Float16 Ks[128][136];
  __shared__ float colred[4][128];
  int tid = threadIdx.x, lane = tid & 63, wave = tid >> 6;
  int mq = lane & 15, quad = lane >> 4;
  int wm = wave * 32;

#pragma unroll
  for (int u = 0; u < 8; ++u) {
    int unit = u * 256 + tid;
    int r = unit >> 4, c8 = (unit & 15) * 8;
    *(half8*)&Ks[r][c8] = *(const half8*)(kh + (size_t)(j0 + r) * 512 + kvh * 128 + c8);
  }
  __syncthreads();

  float colacc[8] = {};
  int n = SEQ / 128 - jb;
  int ib_lo = jb + (sp ? (n >> 1) : 0);
  int ib_hi = jb + (sp ? n : (n >> 1));
  for (int ib = ib_lo; ib < ib_hi; ++ib) {
    int i0 = ib * 128;

    f32x4 acc[2][8] = {};
#pragma unroll
    for (int ks = 0; ks < 4; ++ks) {
      half8 af[2], bf[8];
#pragma unroll
      for (int rt = 0; rt < 2; ++rt)
        af[rt] = *(const half8*)(qh + (size_t)(i0 + wm + rt * 16 + mq) * 2048 + h * 128 + ks * 32 + quad * 8);
#pragma unroll
      for (int ct = 0; ct < 8; ++ct) bf[ct] = *(const half8*)&Ks[ct * 16 + mq][ks * 32 + quad * 8];
#pragma unroll
      for (int rt = 0; rt < 2; ++rt)
#pragma unroll
        for (int ct = 0; ct < 8; ++ct)
          acc[rt][ct] = __builtin_amdgcn_mfma_f32_16x16x32_f16(af[rt], bf[ct], acc[rt][ct], 0, 0, 0);
    }

#pragma unroll
    for (int rt = 0; rt < 2; ++rt) {
      int rbase = i0 + wm + rt * 16 + quad * 4;
      float rm[4], ri[4];
#pragma unroll
      for (int r = 0; r < 4; ++r) {
        rm[r] = rowm[h * SEQ + rbase + r];
        ri[r] = 1.f / rowl[h * SEQ + rbase + r];
      }
#pragma unroll
      for (int ct = 0; ct < 8; ++ct) {
        int j = j0 + ct * 16 + mq;
        float cp = 0.f;
#pragma unroll
        for (int r = 0; r < 4; ++r) {
          if (j <= rbase + r)
            cp += __expf(acc[rt][ct][r] * SCALE - rm[r]) * ri[r];
        }
        colacc[ct] += cp;
      }
    }
  }
#pragma unroll
  for (int ct = 0; ct < 8; ++ct) {
    float v = colacc[ct];
    v += __shfl_xor(v, 16, 64);
    v += __shfl_xor(v, 32, 64);
    colacc[ct] = v;
  }
  __syncthreads();
  if (quad == 0) {
#pragma unroll
    for (int ct = 0; ct < 8; ++ct) colred[wave][ct * 16 + mq] = colacc[ct];
  }
  __syncthreads();
  if (tid < 128)
    colsumP[sp * (NH * SEQ) + h * SEQ + j0 + tid] =
        colred[0][tid] + colred[1][tid] + colred[2][tid] + colred[3][tid];
}

// ---------- top-HEAVY per head via radix select (sums the two colsum partials) ----------
__global__ __launch_bounds__(256) void topk_radix(const float* __restrict__ colsumP,
                                                  int* __restrict__ hidx) {
  int h = blockIdx.x, t = threadIdx.x;
  __shared__ unsigned vals[SEQ];
  __shared__ int hist[256];
  __shared__ int scanbuf[256];
  __shared__ unsigned s_prefix;
  __shared__ int s_k;

  for (int j = t; j < SEQ; j += 256) {
    float cs = colsumP[h * SEQ + j] + colsumP[NH * SEQ + h * SEQ + j];
    vals[j] = __float_as_uint(cs);
  }

  unsigned prefix = 0, maskFixed = 0;
  int k = HEAVY;
  for (int pass = 0; pass < 4; ++pass) {
    int shift = 24 - pass * 8;
    hist[t] = 0;
    __syncthreads();
    for (int j = t; j < SEQ; j += 256) {
      unsigned v = vals[j];
      if ((v & maskFixed) == prefix) atomicAdd(&hist[(v >> shift) & 255], 1);
    }
    __syncthreads();
    if (t == 0) {
      int c = 0, d = 255;
      for (; d > 0; --d) {
        if (c + hist[d] >= k) break;
        c += hist[d];
      }
      s_k = k - c;
      s_prefix = prefix | ((unsigned)d << shift);
    }
    __syncthreads();
    prefix = s_prefix;
    k = s_k;
    maskFixed |= (0xFFu << shift);
    __syncthreads();
  }
  unsigned T = prefix;
  int tieNeed = k;

  int base = t * 8;
  int cG = 0, cT = 0;
#pragma unroll
  for (int u = 0; u < 8; ++u) {
    unsigned v = vals[base + u];
    if (v > T) cG++;
    else if (v == T) cT++;
  }
  scanbuf[t] = cG; __syncthreads();
  for (int off = 1; off < 256; off <<= 1) {
    int x = (t >= off) ? scanbuf[t - off] : 0;
    __syncthreads();
    scanbuf[t] += x;
    __syncthreads();
  }
  int exG = scanbuf[t] - cG;
  int totG = scanbuf[255];
  __syncthreads();
  scanbuf[t] = cT; __syncthreads();
  for (int off = 1; off < 256; off <<= 1) {
    int x = (t >= off) ? scanbuf[t - off] : 0;
    __syncthreads();
    scanbuf[t] += x;
    __syncthreads();
  }
  int exT = scanbuf[t] - cT;

  int slotG = exG;
  int slotT = totG + exT;
#pragma unroll
  for (int u = 0; u < 8; ++u) {
    unsigned v = vals[base + u];
    if (v > T) {
      hidx[h * HEAVY + slotG] = base + u;
      slotG++;
    } else if (v == T) {
      if (slotT < totG + tieNeed) hidx[h * HEAVY + slotT] = base + u;
      slotT++;
    }
  }
}

// ---------- attn3: MFMA sparse flash attention over heavy ∪ recent ----------
__global__ __launch_bounds__(512) void attn3(
    const _Float16* __restrict__ qh, const _Float16* __restrict__ kh,
    const _Float16* __restrict__ vh, const int* __restrict__ hidx,
    _Float16* __restrict__ ctx)
{
  constexpr int TB = 64;
  int i0 = blockIdx.x * 128, h = blockIdx.y, kvh = h >> 2;
  __shared__ _Float16 QP[128][136];       // Q staging; reused as P
  __shared__ _Float16 KVu[9216];          // union: K[64][136] / VT[128][72]
  __shared__ int shx[HEAVY];
  int tid = threadIdx.x, lane = tid & 63, wave = tid >> 6;
  int mq = lane & 15, quad = lane >> 4;
  int wm = wave * 16;

  _Float16 (*Ks)[136] = (_Float16(*)[136])KVu;
  _Float16 (*Vs)[72]  = (_Float16(*)[72])KVu;

#pragma unroll
  for (int u = 0; u < 4; ++u) {
    int unit = u * 512 + tid;
    int r = unit >> 4, c8 = (unit & 15) * 8;
    *(half8*)&QP[r][c8] = *(const half8*)(qh + (size_t)(i0 + r) * 2048 + h * 128 + c8);
  }
  for (int e = tid; e < HEAVY; e += 512) shx[e] = hidx[h * HEAVY + e];
  __syncthreads();

  half8 aq[4];
#pragma unroll
  for (int ks = 0; ks < 4; ++ks) aq[ks] = *(const half8*)&QP[wm + mq][ks * 32 + quad * 8];

  float runm[4], runl[4];
#pragma unroll
  for (int r = 0; r < 4; ++r) { runm[r] = -INFINITY; runl[r] = 0.f; }
  f32x4 acc_o[8] = {};

  int tb_lo = max(0, i0 - RECENT) >> 6;
  int tb_hi = (i0 + 127) >> 6;
  int nband = tb_hi - tb_lo + 1;
  int nheavy = (i0 + 127 > RECENT) ? ((HEAVY + TB - 1) / TB) : 0;
  int ntiles = nband + nheavy;

  for (int tt = 0; tt < ntiles; ++tt) {
    bool isheavy = tt >= nband;
    int j0 = isheavy ? 0 : (tb_lo + tt) * TB;
    int e0 = isheavy ? (tt - nband) * TB : 0;

    // stage K tile (64 cols x 128 dims): lanes write 256B contiguous -> conflict-free
#pragma unroll
    for (int u = 0; u < 2; ++u) {
      int unit = u * 512 + tid;
      int c = unit >> 4, d8 = (unit & 15) * 8;
      int jabs;
      if (!isheavy) jabs = j0 + c;
      else { int e = e0 + c; jabs = (e < HEAVY) ? shx[e] : 0; }
      *(half8*)&Ks[c][d8] = *(const half8*)(kh + (size_t)jabs * 512 + kvh * 128 + d8);
    }
    int jreg[4];
#pragma unroll
    for (int ct = 0; ct < 4; ++ct) {
      int c = ct * 16 + mq;
      if (!isheavy) jreg[ct] = j0 + c;
      else { int e = e0 + c; jreg[ct] = (e < HEAVY) ? shx[e] : (1 << 28); }
    }
    __syncthreads();

    // S = Q K^T
    f32x4 s[4] = {};
#pragma unroll
    for (int ks = 0; ks < 4; ++ks) {
      half8 bf[4];
#pragma unroll
      for (int ct = 0; ct < 4; ++ct) bf[ct] = *(const half8*)&Ks[ct * 16 + mq][ks * 32 + quad * 8];
#pragma unroll
      for (int ct = 0; ct < 4; ++ct)
        s[ct] = __builtin_amdgcn_mfma_f32_16x16x32_f16(aq[ks], bf[ct], s[ct], 0, 0, 0);
    }

    // mask + online softmax
    float p[4][4];
#pragma unroll
    for (int r = 0; r < 4; ++r) {
      int i = i0 + wm + quad * 4 + r;
      float sv[4];
      float mx = -INFINITY;
#pragma unroll
      for (int ct = 0; ct < 4; ++ct) {
        int j = jreg[ct];
        bool ok = isheavy ? (j < i - RECENT) : (j >= i - RECENT && j <= i);
        float x = ok ? s[ct][r] * SCALE : -INFINITY;
        sv[ct] = x;
        mx = fmaxf(mx, x);
      }
      for (int off = 1; off < 16; off <<= 1) mx = fmaxf(mx, __shfl_xor(mx, off, 64));
      float nm = fmaxf(runm[r], mx);
      float sn = (nm == -INFINITY) ? 0.f : nm;
      float alpha = (runm[r] == -INFINITY) ? 0.f : __expf(runm[r] - nm);
      float ps = 0.f;
#pragma unroll
      for (int ct = 0; ct < 4; ++ct) {
        float pe = (sv[ct] == -INFINITY) ? 0.f : __expf(sv[ct] - sn);
        p[ct][r] = pe;
        ps += pe;
      }
      for (int off = 1; off < 16; off <<= 1) ps += __shfl_xor(ps, off, 64);
      runl[r] = runl[r] * alpha + ps;
      runm[r] = nm;
#pragma unroll
      for (int ct = 0; ct < 8; ++ct) acc_o[ct][r] *= alpha;
    }
    __syncthreads();   // all waves done reading Ks

    // stage V^T (overwrites K region): c = lane -> consecutive-column writes, conflict-free
#pragma unroll
    for (int u = 0; u < 2; ++u) {
      int unit = u * 512 + tid;
      int c = unit & 63;           // KV column (lane-consecutive)
      int d8 = (unit >> 6) * 8;    // dim octet
      int jabs;
      if (!isheavy) jabs = j0 + c;
      else { int e = e0 + c; jabs = (e < HEAVY) ? shx[e] : 0; }
      half8 v8 = *(const half8*)(vh + (size_t)jabs * 512 + kvh * 128 + d8);
#pragma unroll
      for (int e2 = 0; e2 < 8; ++e2) Vs[d8 + e2][c] = v8[e2];
    }
#pragma unroll
    for (int ct = 0; ct < 4; ++ct)
#pragma unroll
      for (int r = 0; r < 4; ++r)
        QP[wm + quad * 4 + r][ct * 16 + mq] = (_Float16)p[ct][r];
    __syncthreads();

    // O += P V
#pragma unroll
    for (int ks = 0; ks < 2; ++ks) {
      half8 ap = *(const half8*)&QP[wm + mq][ks * 32 + quad * 8];
      half8 bf[8];
#pragma unroll
      for (int ct = 0; ct < 8; ++ct) bf[ct] = *(const half8*)&Vs[ct * 16 + mq][ks * 32 + quad * 8];
#pragma unroll
      for (int ct = 0; ct < 8; ++ct)
        acc_o[ct] = __builtin_amdgcn_mfma_f32_16x16x32_f16(ap, bf[ct], acc_o[ct], 0, 0, 0);
    }
    __syncthreads();   // done with Vs/QP before next tile staging
  }

  float inv[4];
#pragma unroll
  for (int r = 0; r < 4; ++r) inv[r] = (runl[r] > 0.f) ? 1.f / runl[r] : 0.f;
#pragma unroll
  for (int ct = 0; ct < 8; ++ct) {
    int d = ct * 16 + mq;
#pragma unroll
    for (int r = 0; r < 4; ++r) {
      int i = i0 + wm + quad * 4 + r;
      ctx[(size_t)i * 2048 + h * 128 + d] = (_Float16)(acc_o[ct][r] * inv[r]);
    }
  }
}

// ---------- launch ----------
extern "C" void kernel_launch(void* const* d_in, const int* in_sizes, int n_in,
                              void* d_out, int out_size, void* d_ws, size_t ws_size,
                              hipStream_t stream) {
  const float* hs   = (const float*)d_in[0];
  const float* cosb = (const float*)d_in[1];
  const float* sinb = (const float*)d_in[2];
  const float* Wq = (const float*)d_in[4];
  const float* bq = (const float*)d_in[5];
  const float* Wk = (const float*)d_in[6];
  const float* bk = (const float*)d_in[7];
  const float* Wv = (const float*)d_in[8];
  const float* bv = (const float*)d_in[9];
  const float* Wo = (const float*)d_in[10];
  float* out = (float*)d_out;

  char* ws = (char*)d_ws;
  // lifetimes:  WT(12M) -> [ctxH(8M) + stats block];  qkv(24M) -> WoT(8M);  hsH(8M) -> kh+vh(4M)
  _Float16* WT   = (_Float16*)ws;                       // [3072][2048] f16 12 MB @0
  _Float16* ctxH = (_Float16*)ws;                       // 8 MB @0 (after WT dead)
  float* rowmP   = (float*)(ws + (9u << 20));           // @9M (after WT dead): 2 x NH*SEQ
  float* rowlP   = rowmP + 2 * NH * SEQ;                // 2 x NH*SEQ
  float* rowm    = rowlP + 2 * NH * SEQ;
  float* rowl    = rowm + NH * SEQ;
  float* colsumP = rowl + NH * SEQ;                     // 2 x NH*SEQ
  int*   hidx    = (int*)(colsumP + 2 * NH * SEQ);
  float* qkv     = (float*)(ws + (12u << 20));          // [2048][3072] f32 24 MB @12M
  _Float16* WoT  = (_Float16*)(ws + (12u << 20));       // 8 MB @12M (after qkv dead)
  _Float16* hsH  = (_Float16*)(ws + (36u << 20));       // 8 MB @36M
  _Float16* kh   = (_Float16*)(ws + (36u << 20));       // 2 MB @36M (after hsH dead)
  _Float16* vh   = (_Float16*)(ws + (38u << 20));       // 2 MB @38M
  _Float16* qh   = (_Float16*)(ws + (44u << 20));       // 8 MB @44M
  float* biasqkv = (float*)(ws + (52u << 20));          // 12 KB @52M

  cvt_h<<<(SEQ * 2048 / 4 + 255) / 256, 256, 0, stream>>>(hs, hsH, SEQ * 2048);
  transpose_h<<<dim3(2048 / 64, 2048 / 64), 256, 0, stream>>>(Wq, WT, 2048, 2048);
  transpose_h<<<dim3(512 / 64, 2048 / 64), 256, 0, stream>>>(Wk, WT + (size_t)2048 * 2048, 2048, 512);
  transpose_h<<<dim3(512 / 64, 2048 / 64), 256, 0, stream>>>(Wv, WT + (size_t)2560 * 2048, 2048, 512);
  concat_bias<<<12, 256, 0, stream>>>(bq, bk, bv, biasqkv);

  // fused QKV projection, split-K=2 (atomic accumulate into zeroed qkv)
  hipMemsetAsync(qkv, 0, (size_t)SEQ * 3072 * sizeof(float), stream);
  gemm_h<<<dim3(3072 / 128, 2048 / 128, 2), 256, 0, stream>>>(hsH, WT, biasqkv, qkv, SEQ, 3072, 2048);

  // RoPE + f16 emit (qh/kh/vh); qkv and hsH dead afterwards
  int np = SEQ * 16 * 64 + SEQ * 4 * 64 + SEQ * 4 * 128;
  postproc<<<(np + 255) / 256, 256, 0, stream>>>(qkv, cosb, sinb, qh, kh, vh);

  // Wo transpose into qkv's (now dead) space
  transpose_h<<<dim3(2048 / 64, 2048 / 64), 256, 0, stream>>>(Wo, WoT, 2048, 2048);

  flashstats<<<dim3(2, SEQ / 128, NH), 256, 0, stream>>>(qh, kh, rowmP, rowlP);
  mergestats<<<(NH * SEQ + 255) / 256, 256, 0, stream>>>(rowmP, rowlP, rowm, rowl);
  flashcolsum<<<dim3(2, SEQ / 128, NH), 256, 0, stream>>>(qh, kh, rowm, rowl, colsumP);
  topk_radix<<<NH, 256, 0, stream>>>(colsumP, hidx);
  attn3<<<dim3(SEQ / 128, NH), 512, 0, stream>>>(qh, kh, vh, hidx, ctxH);

  // output projection, split-K=2 (atomic accumulate into zeroed out)
  hipMemsetAsync(out, 0, (size_t)SEQ * 2048 * sizeof(float), stream);
  gemm_h<<<dim3(2048 / 128, 2048 / 128, 2), 256, 0, stream>>>(ctxH, WoT, (const float*)nullptr,
                                                              out, SEQ, 2048, 2048);
}

// Round 2
// 428.387 us; speedup vs baseline: 1.0814x; 1.0814x over previous
//
#include <hip/hip_runtime.h>
#include <hip/hip_bf16.h>
#include <math.h>

constexpr int SEQ    = 2048;
constexpr int NH     = 16;
constexpr int HEAVY  = 204;   // int(0.1*2048)
constexpr int RECENT = 204;   // int(0.1*2048)
constexpr int SPLIT  = 4;     // flash stats/colsum split factor
constexpr float SCALE = 0.08838834764831845f; // 128^-0.5

typedef _Float16 half8 __attribute__((ext_vector_type(8)));
typedef float f32x4 __attribute__((ext_vector_type(4)));

typedef __attribute__((address_space(1))) const void cg_void;
typedef __attribute__((address_space(3))) void l_void;

// ---------- f32 -> f16 convert ----------
__global__ void cvt_h(const float* __restrict__ src, _Float16* __restrict__ dst, int n) {
  int i = (blockIdx.x * 256 + threadIdx.x) * 4;
  if (i + 3 < n) {
    float4 v = *(const float4*)(src + i);
    dst[i] = (_Float16)v.x; dst[i+1] = (_Float16)v.y;
    dst[i+2] = (_Float16)v.z; dst[i+3] = (_Float16)v.w;
  } else {
    for (int u = i; u < n; ++u) dst[u] = (_Float16)src[u];
  }
}

// ---------- transpose + convert: W f32 [K][N] -> WT f16 [N][K] ----------
__global__ __launch_bounds__(256) void transpose_h(
    const float* __restrict__ W, _Float16* __restrict__ WT, int K, int N) {
  __shared__ float T[64][65];
  int c = threadIdx.x & 63, rq = threadIdx.x >> 6;
  int n0 = blockIdx.x * 64, k0 = blockIdx.y * 64;
#pragma unroll
  for (int u = 0; u < 16; ++u) {
    int r = rq * 16 + u;
    T[r][c] = W[(size_t)(k0 + r) * N + n0 + c];
  }
  __syncthreads();
#pragma unroll
  for (int u = 0; u < 16; ++u) {
    int r = rq * 16 + u;
    WT[(size_t)(n0 + r) * K + k0 + c] = (_Float16)T[c][r];
  }
}

// ---------- batched transpose of Wq/Wk/Wv into WT ----------
__global__ __launch_bounds__(256) void transpose_qkv(
    const float* __restrict__ Wq, const float* __restrict__ Wk,
    const float* __restrict__ Wv, _Float16* __restrict__ WT) {
  int z = blockIdx.z;
  const float* W = (z == 0) ? Wq : ((z == 1) ? Wk : Wv);
  int N = (z == 0) ? 2048 : 512;
  size_t dstoff = (z == 0) ? 0 : ((z == 1) ? (size_t)2048 * 2048 : (size_t)2560 * 2048);
  int n0 = blockIdx.x * 64, k0 = blockIdx.y * 64;
  if (n0 >= N) return;
  __shared__ float T[64][65];
  int c = threadIdx.x & 63, rq = threadIdx.x >> 6;
#pragma unroll
  for (int u = 0; u < 16; ++u) {
    int r = rq * 16 + u;
    T[r][c] = W[(size_t)(k0 + r) * N + n0 + c];
  }
  __syncthreads();
#pragma unroll
  for (int u = 0; u < 16; ++u) {
    int r = rq * 16 + u;
    WT[dstoff + (size_t)(n0 + r) * 2048 + k0 + c] = (_Float16)T[c][r];
  }
}

// ---------- concat bias [bq|bk|bv] -> 3072 floats ----------
__global__ void concat_bias(const float* __restrict__ bq, const float* __restrict__ bk,
                            const float* __restrict__ bv, float* __restrict__ b) {
  int i = blockIdx.x * 256 + threadIdx.x;
  if (i < 2048) b[i] = bq[i];
  else if (i < 2560) b[i] = bk[i - 2048];
  else if (i < 3072) b[i] = bv[i - 2560];
}

// ---------- MFMA f16 GEMM, m97 structure: global_load_lds + XOR-swizzled LDS ----------
// LDS layout: linear [128][32] halfs; row r's 4 16B-slots store logical k-slot
// q at stored slot s = q ^ ((r>>1)&3).  Staged by pre-swizzling the per-lane
// GLOBAL k-offset (gll dest is linear lane*16); reads apply the same XOR.
__global__ __launch_bounds__(256) void gemm_h(
    const _Float16* __restrict__ A, const _Float16* __restrict__ BT,
    const float* __restrict__ bias, float* __restrict__ C,
    int M, int N, int K)
{
  __shared__ _Float16 As[128 * 32];
  __shared__ _Float16 Bs[128 * 32];
  int tid = threadIdx.x, lane = tid & 63, wave = tid >> 6;
  int wm = (wave & 1) * 64, wn = (wave >> 1) * 64;
  int m0 = blockIdx.y * 128, n0 = blockIdx.x * 128;
  int mq = lane & 15, quad = lane >> 4;

  f32x4 acc[4][4] = {};

  // staging: wave w covers rows [w*32, w*32+32), two 16-row segments of 1KB
  int rstage = wave * 32 + (lane >> 2);
  int qs = ((lane & 3) ^ ((lane >> 3) & 3)) * 8;   // pre-swizzled k-slot (halfs)
  const _Float16* gA = A  + (size_t)(m0 + rstage) * K + qs;
  const _Float16* gB = BT + (size_t)(n0 + rstage) * K + qs;
  _Float16* lA0 = &As[(wave * 32) * 32];
  _Float16* lA1 = &As[(wave * 32 + 16) * 32];
  _Float16* lB0 = &Bs[(wave * 32) * 32];
  _Float16* lB1 = &Bs[(wave * 32 + 16) * 32];

  int sw = (quad ^ ((mq >> 1) & 3)) * 8;           // read-side swizzled slot (halfs)

  for (int k0 = 0; k0 < K; k0 += 32) {
    __builtin_amdgcn_global_load_lds((cg_void*)(gA + k0),                   (l_void*)lA0, 16, 0, 0);
    __builtin_amdgcn_global_load_lds((cg_void*)(gA + (size_t)16 * K + k0),  (l_void*)lA1, 16, 0, 0);
    __builtin_amdgcn_global_load_lds((cg_void*)(gB + k0),                   (l_void*)lB0, 16, 0, 0);
    __builtin_amdgcn_global_load_lds((cg_void*)(gB + (size_t)16 * K + k0),  (l_void*)lB1, 16, 0, 0);
    __syncthreads();
    half8 af[4], bf[4];
#pragma unroll
    for (int t4 = 0; t4 < 4; ++t4) {
      af[t4] = *(const half8*)&As[(wm + t4 * 16 + mq) * 32 + sw];
      bf[t4] = *(const half8*)&Bs[(wn + t4 * 16 + mq) * 32 + sw];
    }
#pragma unroll
    for (int mt = 0; mt < 4; ++mt)
#pragma unroll
      for (int nt = 0; nt < 4; ++nt)
        acc[mt][nt] = __builtin_amdgcn_mfma_f32_16x16x32_f16(af[mt], bf[nt], acc[mt][nt], 0, 0, 0);
    __syncthreads();
  }

#pragma unroll
  for (int mt = 0; mt < 4; ++mt)
#pragma unroll
    for (int nt = 0; nt < 4; ++nt) {
      int n = n0 + wn + nt * 16 + mq;
      float bb = bias ? bias[n] : 0.f;
#pragma unroll
      for (int r = 0; r < 4; ++r) {
        int m = m0 + wm + mt * 16 + quad * 4 + r;
        C[(size_t)m * N + n] = acc[mt][nt][r] + bb;
      }
    }
}

// ---------- postproc: qkv f32 [s][3072] -> RoPE'd qh/kh + vh (all f16) ----------
__global__ void postproc(const float* __restrict__ qkv, const float* __restrict__ cosb,
                         const float* __restrict__ sinb, _Float16* __restrict__ qh,
                         _Float16* __restrict__ kh, _Float16* __restrict__ vh) {
  int idx = blockIdx.x * 256 + threadIdx.x;
  const int NQ = SEQ * 16 * 64, NK = SEQ * 4 * 64, NV = SEQ * 4 * 128;
  if (idx < NQ) {
    int d = idx & 63; int rest = idx >> 6; int h = rest & 15; int s = rest >> 4;
    const float* p = qkv + (size_t)s * 3072 + h * 128;
    float x1 = p[d], x2 = p[d + 64];
    float c1 = cosb[(size_t)s * 128 + d], c2 = cosb[(size_t)s * 128 + d + 64];
    float s1 = sinb[(size_t)s * 128 + d], s2 = sinb[(size_t)s * 128 + d + 64];
    qh[(size_t)s * 2048 + h * 128 + d]      = (_Float16)(x1 * c1 - x2 * s1);
    qh[(size_t)s * 2048 + h * 128 + d + 64] = (_Float16)(x2 * c2 + x1 * s2);
  } else if (idx < NQ + NK) {
    int r = idx - NQ;
    int d = r & 63; int rest = r >> 6; int h = rest & 3; int s = rest >> 2;
    const float* p = qkv + (size_t)s * 3072 + 2048 + h * 128;
    float x1 = p[d], x2 = p[d + 64];
    float c1 = cosb[(size_t)s * 128 + d], c2 = cosb[(size_t)s * 128 + d + 64];
    float s1 = sinb[(size_t)s * 128 + d], s2 = sinb[(size_t)s * 128 + d + 64];
    kh[(size_t)s * 512 + h * 128 + d]      = (_Float16)(x1 * c1 - x2 * s1);
    kh[(size_t)s * 512 + h * 128 + d + 64] = (_Float16)(x2 * c2 + x1 * s2);
  } else if (idx < NQ + NK + NV) {
    int r = idx - NQ - NK;
    int d = r & 127; int rest = r >> 7; int h = rest & 3; int s = rest >> 2;
    vh[(size_t)s * 512 + h * 128 + d] = (_Float16)qkv[(size_t)s * 3072 + 2560 + h * 128 + d];
  }
}

// ---------- S1: flash row stats (m_i, l_i), Q in registers, j-split ----------
__global__ __launch_bounds__(256) void flashstats(
    const _Float16* __restrict__ qh, const _Float16* __restrict__ kh,
    float* __restrict__ rowmP, float* __restrict__ rowlP)
{
  int sp = blockIdx.x;                    // j-split 0..SPLIT-1
  int ib = blockIdx.y;
  int i0 = ib * 128, h = blockIdx.z, kvh = h >> 2;
  __shared__ _Float16 Ks[128][136];
  int tid = threadIdx.x, lane = tid & 63, wave = tid >> 6;
  int mq = lane & 15, quad = lane >> 4;
  int wm = wave * 32;

  // Q fragments held in registers (per-lane MFMA A-fragment, loaded once)
  half8 aq[2][4];
#pragma unroll
  for (int rt = 0; rt < 2; ++rt)
#pragma unroll
    for (int ks = 0; ks < 4; ++ks)
      aq[rt][ks] = *(const half8*)(qh + (size_t)(i0 + wm + rt * 16 + mq) * 2048 + h * 128 + ks * 32 + quad * 8);

  float runm[2][4], runl[2][4];
#pragma unroll
  for (int rt = 0; rt < 2; ++rt)
#pragma unroll
    for (int r = 0; r < 4; ++r) { runm[rt][r] = -INFINITY; runl[rt][r] = 0.f; }

  int nblk = ib + 1;
  int jb_lo = (sp * nblk) / SPLIT;
  int jb_hi = ((sp + 1) * nblk) / SPLIT;
  for (int jb = jb_lo; jb < jb_hi; ++jb) {
    int j0 = jb * 128;
    __syncthreads();
#pragma unroll
    for (int u = 0; u < 8; ++u) {
      int unit = u * 256 + tid;
      int r = unit >> 4, c8 = (unit & 15) * 8;
      *(half8*)&Ks[r][c8] = *(const half8*)(kh + (size_t)(j0 + r) * 512 + kvh * 128 + c8);
    }
    __syncthreads();

    f32x4 acc[2][8] = {};
#pragma unroll
    for (int ks = 0; ks < 4; ++ks) {
      half8 bf[8];
#pragma unroll
      for (int ct = 0; ct < 8; ++ct) bf[ct] = *(const half8*)&Ks[ct * 16 + mq][ks * 32 + quad * 8];
#pragma unroll
      for (int rt = 0; rt < 2; ++rt)
#pragma unroll
        for (int ct = 0; ct < 8; ++ct)
          acc[rt][ct] = __builtin_amdgcn_mfma_f32_16x16x32_f16(aq[rt][ks], bf[ct], acc[rt][ct], 0, 0, 0);
    }

#pragma unroll
    for (int rt = 0; rt < 2; ++rt) {
      int rbase = i0 + wm + rt * 16 + quad * 4;
#pragma unroll
      for (int ct = 0; ct < 8; ++ct) {
        int j = j0 + ct * 16 + mq;
#pragma unroll
        for (int r = 0; r < 4; ++r) {
          float s = acc[rt][ct][r] * SCALE;
          if (j > rbase + r) s = -INFINITY;
          acc[rt][ct][r] = s;
        }
      }
#pragma unroll
      for (int r = 0; r < 4; ++r) {
        float v = acc[rt][0][r];
#pragma unroll
        for (int ct = 1; ct < 8; ++ct) v = fmaxf(v, acc[rt][ct][r]);
        for (int off = 1; off < 16; off <<= 1) v = fmaxf(v, __shfl_xor(v, off, 64));
        float nm = fmaxf(runm[rt][r], v);
        float alpha = (runm[rt][r] == -INFINITY) ? 0.f : __expf(runm[rt][r] - nm);
        float ps = 0.f;
#pragma unroll
        for (int ct = 0; ct < 8; ++ct) ps += __expf(acc[rt][ct][r] - nm);
        for (int off = 1; off < 16; off <<= 1) ps += __shfl_xor(ps, off, 64);
        runl[rt][r] = runl[rt][r] * alpha + ps;
        runm[rt][r] = nm;
      }
    }
  }
  if (mq == 0) {
#pragma unroll
    for (int rt = 0; rt < 2; ++rt)
#pragma unroll
      for (int r = 0; r < 4; ++r) {
        int i = i0 + wm + rt * 16 + quad * 4 + r;
        rowmP[sp * (NH * SEQ) + h * SEQ + i] = runm[rt][r];
        rowlP[sp * (NH * SEQ) + h * SEQ + i] = runl[rt][r];
      }
  }
}

// ---------- merge split row stats ----------
__global__ void mergestats(const float* __restrict__ rowmP, const float* __restrict__ rowlP,
                           float* __restrict__ rowm, float* __restrict__ rowl) {
  int i = blockIdx.x * 256 + threadIdx.x;
  if (i >= NH * SEQ) return;
  float m = -INFINITY;
#pragma unroll
  for (int s = 0; s < SPLIT; ++s) m = fmaxf(m, rowmP[s * (NH * SEQ) + i]);
  float l = 0.f;
#pragma unroll
  for (int s = 0; s < SPLIT; ++s) {
    float ls = rowlP[s * (NH * SEQ) + i];
    if (ls > 0.f) l += ls * __expf(rowmP[s * (NH * SEQ) + i] - m);
  }
  rowm[i] = m; rowl[i] = l;
}

// ---------- S2: colsum[h][j] = sum_i exp(s_ij - m_i)/l_i, Q streamed, i-split ----------
__global__ __launch_bounds__(256) void flashcolsum(
    const _Float16* __restrict__ qh, const _Float16* __restrict__ kh,
    const float* __restrict__ rowm, const float* __restrict__ rowl,
    float* __restrict__ colsumP)
{
  int sp = blockIdx.x;                    // i-split 0..SPLIT-1
  int jb = blockIdx.y;
  int j0 = jb * 128, h = blockIdx.z, kvh = h >> 2;
  __shared__ _Float16 Ks[128][136];
  __shared__ float colred[4][128];
  int tid = threadIdx.x, lane = tid & 63, wave = tid >> 6;
  int mq = lane & 15, quad = lane >> 4;
  int wm = wave * 32;

#pragma unroll
  for (int u = 0; u < 8; ++u) {
    int unit = u * 256 + tid;
    int r = unit >> 4, c8 = (unit & 15) * 8;
    *(half8*)&Ks[r][c8] = *(const half8*)(kh + (size_t)(j0 + r) * 512 + kvh * 128 + c8);
  }
  __syncthreads();

  float colacc[8] = {};
  int n = SEQ / 128 - jb;
  int ib_lo = jb + (sp * n) / SPLIT;
  int ib_hi = jb + ((sp + 1) * n) / SPLIT;
  for (int ib = ib_lo; ib < ib_hi; ++ib) {
    int i0 = ib * 128;

    f32x4 acc[2][8] = {};
#pragma unroll
    for (int ks = 0; ks < 4; ++ks) {
      half8 af[2], bf[8];
#pragma unroll
      for (int rt = 0; rt < 2; ++rt)
        af[rt] = *(const half8*)(qh + (size_t)(i0 + wm + rt * 16 + mq) * 2048 + h * 128 + ks * 32 + quad * 8);
#pragma unroll
      for (int ct = 0; ct < 8; ++ct) bf[ct] = *(const half8*)&Ks[ct * 16 + mq][ks * 32 + quad * 8];
#pragma unroll
      for (int rt = 0; rt < 2; ++rt)
#pragma unroll
        for (int ct = 0; ct < 8; ++ct)
          acc[rt][ct] = __builtin_amdgcn_mfma_f32_16x16x32_f16(af[rt], bf[ct], acc[rt][ct], 0, 0, 0);
    }

#pragma unroll
    for (int rt = 0; rt < 2; ++rt) {
      int rbase = i0 + wm + rt * 16 + quad * 4;
      float rm[4], ri[4];
#pragma unroll
      for (int r = 0; r < 4; ++r) {
        rm[r] = rowm[h * SEQ + rbase + r];
        ri[r] = 1.f / rowl[h * SEQ + rbase + r];
      }
#pragma unroll
      for (int ct = 0; ct < 8; ++ct) {
        int j = j0 + ct * 16 + mq;
        float cp = 0.f;
#pragma unroll
        for (int r = 0; r < 4; ++r) {
          if (j <= rbase + r)
            cp += __expf(acc[rt][ct][r] * SCALE - rm[r]) * ri[r];
        }
        colacc[ct] += cp;
      }
    }
  }
#pragma unroll
  for (int ct = 0; ct < 8; ++ct) {
    float v = colacc[ct];
    v += __shfl_xor(v, 16, 64);
    v += __shfl_xor(v, 32, 64);
    colacc[ct] = v;
  }
  __syncthreads();
  if (quad == 0) {
#pragma unroll
    for (int ct = 0; ct < 8; ++ct) colred[wave][ct * 16 + mq] = colacc[ct];
  }
  __syncthreads();
  if (tid < 128)
    colsumP[sp * (NH * SEQ) + h * SEQ + j0 + tid] =
        colred[0][tid] + colred[1][tid] + colred[2][tid] + colred[3][tid];
}

// ---------- top-HEAVY per head via radix select (sums the colsum partials) ----------
__global__ __launch_bounds__(256) void topk_radix(const float* __restrict__ colsumP,
                                                  int* __restrict__ hidx) {
  int h = blockIdx.x, t = threadIdx.x;
  __shared__ unsigned vals[SEQ];
  __shared__ int hist[256];
  __shared__ int scanbuf[256];
  __shared__ unsigned s_prefix;
  __shared__ int s_k;

  for (int j = t; j < SEQ; j += 256) {
    float cs = 0.f;
#pragma unroll
    for (int s = 0; s < SPLIT; ++s) cs += colsumP[s * (NH * SEQ) + h * SEQ + j];
    vals[j] = __float_as_uint(cs);
  }

  unsigned prefix = 0, maskFixed = 0;
  int k = HEAVY;
  for (int pass = 0; pass < 4; ++pass) {
    int shift = 24 - pass * 8;
    hist[t] = 0;
    __syncthreads();
    for (int j = t; j < SEQ; j += 256) {
      unsigned v = vals[j];
      if ((v & maskFixed) == prefix) atomicAdd(&hist[(v >> shift) & 255], 1);
    }
    __syncthreads();
    if (t == 0) {
      int c = 0, d = 255;
      for (; d > 0; --d) {
        if (c + hist[d] >= k) break;
        c += hist[d];
      }
      s_k = k - c;
      s_prefix = prefix | ((unsigned)d << shift);
    }
    __syncthreads();
    prefix = s_prefix;
    k = s_k;
    maskFixed |= (0xFFu << shift);
    __syncthreads();
  }
  unsigned T = prefix;
  int tieNeed = k;

  int base = t * 8;
  int cG = 0, cT = 0;
#pragma unroll
  for (int u = 0; u < 8; ++u) {
    unsigned v = vals[base + u];
    if (v > T) cG++;
    else if (v == T) cT++;
  }
  scanbuf[t] = cG; __syncthreads();
  for (int off = 1; off < 256; off <<= 1) {
    int x = (t >= off) ? scanbuf[t - off] : 0;
    __syncthreads();
    scanbuf[t] += x;
    __syncthreads();
  }
  int exG = scanbuf[t] - cG;
  int totG = scanbuf[255];
  __syncthreads();
  scanbuf[t] = cT; __syncthreads();
  for (int off = 1; off < 256; off <<= 1) {
    int x = (t >= off) ? scanbuf[t - off] : 0;
    __syncthreads();
    scanbuf[t] += x;
    __syncthreads();
  }
  int exT = scanbuf[t] - cT;

  int slotG = exG;
  int slotT = totG + exT;
#pragma unroll
  for (int u = 0; u < 8; ++u) {
    unsigned v = vals[base + u];
    if (v > T) {
      hidx[h * HEAVY + slotG] = base + u;
      slotG++;
    } else if (v == T) {
      if (slotT < totG + tieNeed) hidx[h * HEAVY + slotT] = base + u;
      slotT++;
    }
  }
}

// ---------- attn3: MFMA sparse flash attention over heavy ∪ recent ----------
__global__ __launch_bounds__(512) void attn3(
    const _Float16* __restrict__ qh, const _Float16* __restrict__ kh,
    const _Float16* __restrict__ vh, const int* __restrict__ hidx,
    _Float16* __restrict__ ctx)
{
  constexpr int TB = 64;
  int i0 = blockIdx.x * 128, h = blockIdx.y, kvh = h >> 2;
  __shared__ _Float16 QP[128][136];       // Q staging; reused as P
  __shared__ _Float16 KVu[9216];          // union: K[64][136] / VT[128][72]
  __shared__ int shx[HEAVY];
  int tid = threadIdx.x, lane = tid & 63, wave = tid >> 6;
  int mq = lane & 15, quad = lane >> 4;
  int wm = wave * 16;

  _Float16 (*Ks)[136] = (_Float16(*)[136])KVu;
  _Float16 (*Vs)[72]  = (_Float16(*)[72])KVu;

#pragma unroll
  for (int u = 0; u < 4; ++u) {
    int unit = u * 512 + tid;
    int r = unit >> 4, c8 = (unit & 15) * 8;
    *(half8*)&QP[r][c8] = *(const half8*)(qh + (size_t)(i0 + r) * 2048 + h * 128 + c8);
  }
  for (int e = tid; e < HEAVY; e += 512) shx[e] = hidx[h * HEAVY + e];
  __syncthreads();

  half8 aq[4];
#pragma unroll
  for (int ks = 0; ks < 4; ++ks) aq[ks] = *(const half8*)&QP[wm + mq][ks * 32 + quad * 8];

  float runm[4], runl[4];
#pragma unroll
  for (int r = 0; r < 4; ++r) { runm[r] = -INFINITY; runl[r] = 0.f; }
  f32x4 acc_o[8] = {};

  int tb_lo = max(0, i0 - RECENT) >> 6;
  int tb_hi = (i0 + 127) >> 6;
  int nband = tb_hi - tb_lo + 1;
  int nheavy = (i0 + 127 > RECENT) ? ((HEAVY + TB - 1) / TB) : 0;
  int ntiles = nband + nheavy;

  for (int tt = 0; tt < ntiles; ++tt) {
    bool isheavy = tt >= nband;
    int j0 = isheavy ? 0 : (tb_lo + tt) * TB;
    int e0 = isheavy ? (tt - nband) * TB : 0;

    // stage K tile (64 cols x 128 dims): lanes write 256B contiguous -> conflict-free
#pragma unroll
    for (int u = 0; u < 2; ++u) {
      int unit = u * 512 + tid;
      int c = unit >> 4, d8 = (unit & 15) * 8;
      int jabs;
      if (!isheavy) jabs = j0 + c;
      else { int e = e0 + c; jabs = (e < HEAVY) ? shx[e] : 0; }
      *(half8*)&Ks[c][d8] = *(const half8*)(kh + (size_t)jabs * 512 + kvh * 128 + d8);
    }
    int jreg[4];
#pragma unroll
    for (int ct = 0; ct < 4; ++ct) {
      int c = ct * 16 + mq;
      if (!isheavy) jreg[ct] = j0 + c;
      else { int e = e0 + c; jreg[ct] = (e < HEAVY) ? shx[e] : (1 << 28); }
    }
    __syncthreads();

    // S = Q K^T
    f32x4 s[4] = {};
#pragma unroll
    for (int ks = 0; ks < 4; ++ks) {
      half8 bf[4];
#pragma unroll
      for (int ct = 0; ct < 4; ++ct) bf[ct] = *(const half8*)&Ks[ct * 16 + mq][ks * 32 + quad * 8];
#pragma unroll
      for (int ct = 0; ct < 4; ++ct)
        s[ct] = __builtin_amdgcn_mfma_f32_16x16x32_f16(aq[ks], bf[ct], s[ct], 0, 0, 0);
    }

    // mask + online softmax
    float p[4][4];
#pragma unroll
    for (int r = 0; r < 4; ++r) {
      int i = i0 + wm + quad * 4 + r;
      float sv[4];
      float mx = -INFINITY;
#pragma unroll
      for (int ct = 0; ct < 4; ++ct) {
        int j = jreg[ct];
        bool ok = isheavy ? (j < i - RECENT) : (j >= i - RECENT && j <= i);
        float x = ok ? s[ct][r] * SCALE : -INFINITY;
        sv[ct] = x;
        mx = fmaxf(mx, x);
      }
      for (int off = 1; off < 16; off <<= 1) mx = fmaxf(mx, __shfl_xor(mx, off, 64));
      float nm = fmaxf(runm[r], mx);
      float sn = (nm == -INFINITY) ? 0.f : nm;
      float alpha = (runm[r] == -INFINITY) ? 0.f : __expf(runm[r] - nm);
      float ps = 0.f;
#pragma unroll
      for (int ct = 0; ct < 4; ++ct) {
        float pe = (sv[ct] == -INFINITY) ? 0.f : __expf(sv[ct] - sn);
        p[ct][r] = pe;
        ps += pe;
      }
      for (int off = 1; off < 16; off <<= 1) ps += __shfl_xor(ps, off, 64);
      runl[r] = runl[r] * alpha + ps;
      runm[r] = nm;
#pragma unroll
      for (int ct = 0; ct < 8; ++ct) acc_o[ct][r] *= alpha;
    }
    __syncthreads();   // all waves done reading Ks

    // stage V^T (overwrites K region): c = lane -> consecutive-column writes, conflict-free
#pragma unroll
    for (int u = 0; u < 2; ++u) {
      int unit = u * 512 + tid;
      int c = unit & 63;           // KV column (lane-consecutive)
      int d8 = (unit >> 6) * 8;    // dim octet
      int jabs;
      if (!isheavy) jabs = j0 + c;
      else { int e = e0 + c; jabs = (e < HEAVY) ? shx[e] : 0; }
      half8 v8 = *(const half8*)(vh + (size_t)jabs * 512 + kvh * 128 + d8);
#pragma unroll
      for (int e2 = 0; e2 < 8; ++e2) Vs[d8 + e2][c] = v8[e2];
    }
#pragma unroll
    for (int ct = 0; ct < 4; ++ct)
#pragma unroll
      for (int r = 0; r < 4; ++r)
        QP[wm + quad * 4 + r][ct * 16 + mq] = (_Float16)p[ct][r];
    __syncthreads();

    // O += P V
#pragma unroll
    for (int ks = 0; ks < 2; ++ks) {
      half8 ap = *(const half8*)&QP[wm + mq][ks * 32 + quad * 8];
      half8 bf[8];
#pragma unroll
      for (int ct = 0; ct < 8; ++ct) bf[ct] = *(const half8*)&Vs[ct * 16 + mq][ks * 32 + quad * 8];
#pragma unroll
      for (int ct = 0; ct < 8; ++ct)
        acc_o[ct] = __builtin_amdgcn_mfma_f32_16x16x32_f16(ap, bf[ct], acc_o[ct], 0, 0, 0);
    }
    __syncthreads();   // done with Vs/QP before next tile staging
  }

  float inv[4];
#pragma unroll
  for (int r = 0; r < 4; ++r) inv[r] = (runl[r] > 0.f) ? 1.f / runl[r] : 0.f;
#pragma unroll
  for (int ct = 0; ct < 8; ++ct) {
    int d = ct * 16 + mq;
#pragma unroll
    for (int r = 0; r < 4; ++r) {
      int i = i0 + wm + quad * 4 + r;
      ctx[(size_t)i * 2048 + h * 128 + d] = (_Float16)(acc_o[ct][r] * inv[r]);
    }
  }
}

// ---------- launch ----------
extern "C" void kernel_launch(void* const* d_in, const int* in_sizes, int n_in,
                              void* d_out, int out_size, void* d_ws, size_t ws_size,
                              hipStream_t stream) {
  const float* hs   = (const float*)d_in[0];
  const float* cosb = (const float*)d_in[1];
  const float* sinb = (const float*)d_in[2];
  const float* Wq = (const float*)d_in[4];
  const float* bq = (const float*)d_in[5];
  const float* Wk = (const float*)d_in[6];
  const float* bk = (const float*)d_in[7];
  const float* Wv = (const float*)d_in[8];
  const float* bv = (const float*)d_in[9];
  const float* Wo = (const float*)d_in[10];
  float* out = (float*)d_out;

  char* ws = (char*)d_ws;
  // lifetimes:  WT(12M) -> [ctxH(8M) + stats block];  qkv(24M) -> WoT(8M);  hsH(8M) -> kh+vh(4M)
  _Float16* WT   = (_Float16*)ws;                       // [3072][2048] f16 12 MB @0
  _Float16* ctxH = (_Float16*)ws;                       // 8 MB @0 (after WT dead)
  float* rowmP   = (float*)(ws + (9u << 20));           // @9M (after WT dead): SPLIT x NH*SEQ
  float* rowlP   = rowmP + SPLIT * NH * SEQ;
  float* rowm    = rowlP + SPLIT * NH * SEQ;
  float* rowl    = rowm + NH * SEQ;
  float* colsumP = rowl + NH * SEQ;                     // SPLIT x NH*SEQ
  int*   hidx    = (int*)(colsumP + SPLIT * NH * SEQ);
  float* qkv     = (float*)(ws + (12u << 20));          // [2048][3072] f32 24 MB @12M
  _Float16* WoT  = (_Float16*)(ws + (12u << 20));       // 8 MB @12M (after qkv dead)
  _Float16* hsH  = (_Float16*)(ws + (36u << 20));       // 8 MB @36M
  _Float16* kh   = (_Float16*)(ws + (36u << 20));       // 2 MB @36M (after hsH dead)
  _Float16* vh   = (_Float16*)(ws + (38u << 20));       // 2 MB @38M
  _Float16* qh   = (_Float16*)(ws + (44u << 20));       // 8 MB @44M
  float* biasqkv = (float*)(ws + (52u << 20));          // 12 KB @52M

  cvt_h<<<(SEQ * 2048 / 4 + 255) / 256, 256, 0, stream>>>(hs, hsH, SEQ * 2048);
  transpose_qkv<<<dim3(2048 / 64, 2048 / 64, 3), 256, 0, stream>>>(Wq, Wk, Wv, WT);
  concat_bias<<<12, 256, 0, stream>>>(bq, bk, bv, biasqkv);

  // fused QKV projection: [2048][2048] x [3072][2048]^T -> qkv [2048][3072]
  gemm_h<<<dim3(3072 / 128, 2048 / 128), 256, 0, stream>>>(hsH, WT, biasqkv, qkv, SEQ, 3072, 2048);

  // RoPE + f16 emit (qh/kh/vh); qkv and hsH dead afterwards
  int np = SEQ * 16 * 64 + SEQ * 4 * 64 + SEQ * 4 * 128;
  postproc<<<(np + 255) / 256, 256, 0, stream>>>(qkv, cosb, sinb, qh, kh, vh);

  // Wo transpose into qkv's (now dead) space
  transpose_h<<<dim3(2048 / 64, 2048 / 64), 256, 0, stream>>>(Wo, WoT, 2048, 2048);

  flashstats<<<dim3(SPLIT, SEQ / 128, NH), 256, 0, stream>>>(qh, kh, rowmP, rowlP);
  mergestats<<<(NH * SEQ + 255) / 256, 256, 0, stream>>>(rowmP, rowlP, rowm, rowl);
  flashcolsum<<<dim3(SPLIT, SEQ / 128, NH), 256, 0, stream>>>(qh, kh, rowm, rowl, colsumP);
  topk_radix<<<NH, 256, 0, stream>>>(colsumP, hidx);
  attn3<<<dim3(SEQ / 128, NH), 512, 0, stream>>>(qh, kh, vh, hidx, ctxH);

  // output projection
  gemm_h<<<dim3(2048 / 128, 2048 / 128), 256, 0, stream>>>(ctxH, WoT, (const float*)nullptr,
                                                           out, SEQ, 2048, 2048);
}

// Round 3
// 421.988 us; speedup vs baseline: 1.0978x; 1.0152x over previous
//
#include <hip/hip_runtime.h>
#include <hip/hip_bf16.h>
#include <math.h>

constexpr int SEQ    = 2048;
constexpr int NH     = 16;
constexpr int HEAVY  = 204;   // int(0.1*2048)
constexpr int RECENT = 204;   // int(0.1*2048)
constexpr int SPLIT  = 4;     // flash stats/colsum split factor
constexpr float SCALE = 0.08838834764831845f; // 128^-0.5

typedef _Float16 half8 __attribute__((ext_vector_type(8)));
typedef float f32x4 __attribute__((ext_vector_type(4)));

typedef __attribute__((address_space(1))) const void cg_void;
typedef __attribute__((address_space(3))) void l_void;

// ---------- f32 -> f16 convert ----------
__global__ void cvt_h(const float* __restrict__ src, _Float16* __restrict__ dst, int n) {
  int i = (blockIdx.x * 256 + threadIdx.x) * 4;
  if (i + 3 < n) {
    float4 v = *(const float4*)(src + i);
    dst[i] = (_Float16)v.x; dst[i+1] = (_Float16)v.y;
    dst[i+2] = (_Float16)v.z; dst[i+3] = (_Float16)v.w;
  } else {
    for (int u = i; u < n; ++u) dst[u] = (_Float16)src[u];
  }
}

// ---------- transpose + convert: W f32 [K][N] -> WT f16 [N][K] ----------
__global__ __launch_bounds__(256) void transpose_h(
    const float* __restrict__ W, _Float16* __restrict__ WT, int K, int N) {
  __shared__ float T[64][65];
  int c = threadIdx.x & 63, rq = threadIdx.x >> 6;
  int n0 = blockIdx.x * 64, k0 = blockIdx.y * 64;
#pragma unroll
  for (int u = 0; u < 16; ++u) {
    int r = rq * 16 + u;
    T[r][c] = W[(size_t)(k0 + r) * N + n0 + c];
  }
  __syncthreads();
#pragma unroll
  for (int u = 0; u < 16; ++u) {
    int r = rq * 16 + u;
    WT[(size_t)(n0 + r) * K + k0 + c] = (_Float16)T[c][r];
  }
}

// ---------- batched transpose of Wq/Wk/Wv into WT ----------
__global__ __launch_bounds__(256) void transpose_qkv(
    const float* __restrict__ Wq, const float* __restrict__ Wk,
    const float* __restrict__ Wv, _Float16* __restrict__ WT) {
  int z = blockIdx.z;
  const float* W = (z == 0) ? Wq : ((z == 1) ? Wk : Wv);
  int N = (z == 0) ? 2048 : 512;
  size_t dstoff = (z == 0) ? 0 : ((z == 1) ? (size_t)2048 * 2048 : (size_t)2560 * 2048);
  int n0 = blockIdx.x * 64, k0 = blockIdx.y * 64;
  if (n0 >= N) return;
  __shared__ float T[64][65];
  int c = threadIdx.x & 63, rq = threadIdx.x >> 6;
#pragma unroll
  for (int u = 0; u < 16; ++u) {
    int r = rq * 16 + u;
    T[r][c] = W[(size_t)(k0 + r) * N + n0 + c];
  }
  __syncthreads();
#pragma unroll
  for (int u = 0; u < 16; ++u) {
    int r = rq * 16 + u;
    WT[dstoff + (size_t)(n0 + r) * 2048 + k0 + c] = (_Float16)T[c][r];
  }
}

// ---------- concat bias [bq|bk|bv] -> 3072 floats ----------
__global__ void concat_bias(const float* __restrict__ bq, const float* __restrict__ bk,
                            const float* __restrict__ bv, float* __restrict__ b) {
  int i = blockIdx.x * 256 + threadIdx.x;
  if (i < 2048) b[i] = bq[i];
  else if (i < 2560) b[i] = bk[i - 2048];
  else if (i < 3072) b[i] = bv[i - 2560];
}

// ---------- MFMA f16 GEMM, m97 structure, split-K via gridDim.z into SEPARATE buffers ----------
// LDS: linear [128][32] halfs, XOR-swizzled k-slots (pre-swizzled global src + swizzled read).
__global__ __launch_bounds__(256) void gemm_h(
    const _Float16* __restrict__ A, const _Float16* __restrict__ BT,
    const float* __restrict__ bias, float* __restrict__ C0, float* __restrict__ C1,
    int M, int N, int K)
{
  __shared__ _Float16 As[128 * 32];
  __shared__ _Float16 Bs[128 * 32];
  int tid = threadIdx.x, lane = tid & 63, wave = tid >> 6;
  int wm = (wave & 1) * 64, wn = (wave >> 1) * 64;
  int m0 = blockIdx.y * 128, n0 = blockIdx.x * 128;
  int mq = lane & 15, quad = lane >> 4;
  int kz = blockIdx.z, nz = gridDim.z;
  int kchunk = K / nz;
  int kbeg = kz * kchunk, kend = kbeg + kchunk;
  float* C = kz ? C1 : C0;

  f32x4 acc[4][4] = {};

  // staging: wave w covers rows [w*32, w*32+32), two 16-row segments of 1KB
  int rstage = wave * 32 + (lane >> 2);
  int qs = ((lane & 3) ^ ((lane >> 3) & 3)) * 8;   // pre-swizzled k-slot (halfs)
  const _Float16* gA = A  + (size_t)(m0 + rstage) * K + qs;
  const _Float16* gB = BT + (size_t)(n0 + rstage) * K + qs;
  _Float16* lA0 = &As[(wave * 32) * 32];
  _Float16* lA1 = &As[(wave * 32 + 16) * 32];
  _Float16* lB0 = &Bs[(wave * 32) * 32];
  _Float16* lB1 = &Bs[(wave * 32 + 16) * 32];

  int sw = (quad ^ ((mq >> 1) & 3)) * 8;           // read-side swizzled slot (halfs)

  for (int k0 = kbeg; k0 < kend; k0 += 32) {
    __builtin_amdgcn_global_load_lds((cg_void*)(gA + k0),                   (l_void*)lA0, 16, 0, 0);
    __builtin_amdgcn_global_load_lds((cg_void*)(gA + (size_t)16 * K + k0),  (l_void*)lA1, 16, 0, 0);
    __builtin_amdgcn_global_load_lds((cg_void*)(gB + k0),                   (l_void*)lB0, 16, 0, 0);
    __builtin_amdgcn_global_load_lds((cg_void*)(gB + (size_t)16 * K + k0),  (l_void*)lB1, 16, 0, 0);
    __syncthreads();
    half8 af[4], bf[4];
#pragma unroll
    for (int t4 = 0; t4 < 4; ++t4) {
      af[t4] = *(const half8*)&As[(wm + t4 * 16 + mq) * 32 + sw];
      bf[t4] = *(const half8*)&Bs[(wn + t4 * 16 + mq) * 32 + sw];
    }
#pragma unroll
    for (int mt = 0; mt < 4; ++mt)
#pragma unroll
      for (int nt = 0; nt < 4; ++nt)
        acc[mt][nt] = __builtin_amdgcn_mfma_f32_16x16x32_f16(af[mt], bf[nt], acc[mt][nt], 0, 0, 0);
    __syncthreads();
  }

#pragma unroll
  for (int mt = 0; mt < 4; ++mt)
#pragma unroll
    for (int nt = 0; nt < 4; ++nt) {
      int n = n0 + wn + nt * 16 + mq;
      float bb = (bias && kz == 0) ? bias[n] : 0.f;
#pragma unroll
      for (int r = 0; r < 4; ++r) {
        int m = m0 + wm + mt * 16 + quad * 4 + r;
        C[(size_t)m * N + n] = acc[mt][nt][r] + bb;
      }
    }
}

// ---------- add partial into out ----------
__global__ void addout(float* __restrict__ out, const float* __restrict__ p1, int n) {
  int i = (blockIdx.x * 256 + threadIdx.x) * 4;
  if (i + 3 < n) {
    float4 a = *(const float4*)(out + i);
    float4 b = *(const float4*)(p1 + i);
    a.x += b.x; a.y += b.y; a.z += b.z; a.w += b.w;
    *(float4*)(out + i) = a;
  } else {
    for (int u = i; u < n; ++u) out[u] += p1[u];
  }
}

// ---------- postproc: qkv partials f32 [s][3072] -> RoPE'd qh/kh + vh (all f16) ----------
__global__ void postproc(const float* __restrict__ qkv, const float* __restrict__ qkv1,
                         const float* __restrict__ cosb, const float* __restrict__ sinb,
                         _Float16* __restrict__ qh, _Float16* __restrict__ kh,
                         _Float16* __restrict__ vh) {
  int idx = blockIdx.x * 256 + threadIdx.x;
  const int NQ = SEQ * 16 * 64, NK = SEQ * 4 * 64, NV = SEQ * 4 * 128;
  bool sp = (qkv1 != nullptr);
  if (idx < NQ) {
    int d = idx & 63; int rest = idx >> 6; int h = rest & 15; int s = rest >> 4;
    size_t o = (size_t)s * 3072 + h * 128;
    float x1 = qkv[o + d]      + (sp ? qkv1[o + d] : 0.f);
    float x2 = qkv[o + d + 64] + (sp ? qkv1[o + d + 64] : 0.f);
    float c1 = cosb[(size_t)s * 128 + d], c2 = cosb[(size_t)s * 128 + d + 64];
    float s1 = sinb[(size_t)s * 128 + d], s2 = sinb[(size_t)s * 128 + d + 64];
    qh[(size_t)s * 2048 + h * 128 + d]      = (_Float16)(x1 * c1 - x2 * s1);
    qh[(size_t)s * 2048 + h * 128 + d + 64] = (_Float16)(x2 * c2 + x1 * s2);
  } else if (idx < NQ + NK) {
    int r = idx - NQ;
    int d = r & 63; int rest = r >> 6; int h = rest & 3; int s = rest >> 2;
    size_t o = (size_t)s * 3072 + 2048 + h * 128;
    float x1 = qkv[o + d]      + (sp ? qkv1[o + d] : 0.f);
    float x2 = qkv[o + d + 64] + (sp ? qkv1[o + d + 64] : 0.f);
    float c1 = cosb[(size_t)s * 128 + d], c2 = cosb[(size_t)s * 128 + d + 64];
    float s1 = sinb[(size_t)s * 128 + d], s2 = sinb[(size_t)s * 128 + d + 64];
    kh[(size_t)s * 512 + h * 128 + d]      = (_Float16)(x1 * c1 - x2 * s1);
    kh[(size_t)s * 512 + h * 128 + d + 64] = (_Float16)(x2 * c2 + x1 * s2);
  } else if (idx < NQ + NK + NV) {
    int r = idx - NQ - NK;
    int d = r & 127; int rest = r >> 7; int h = rest & 3; int s = rest >> 2;
    size_t o = (size_t)s * 3072 + 2560 + h * 128 + d;
    float x = qkv[o] + (sp ? qkv1[o] : 0.f);
    vh[(size_t)s * 512 + h * 128 + d] = (_Float16)x;
  }
}

// ---------- S1: flash row stats (m_i, l_i), Q in registers, per-lane online, j-split ----------
__global__ __launch_bounds__(256) void flashstats(
    const _Float16* __restrict__ qh, const _Float16* __restrict__ kh,
    float* __restrict__ rowmP, float* __restrict__ rowlP)
{
  int sp = blockIdx.x;                    // j-split 0..SPLIT-1
  int ib = blockIdx.y;
  int i0 = ib * 128, h = blockIdx.z, kvh = h >> 2;
  __shared__ _Float16 Ks[128][136];
  int tid = threadIdx.x, lane = tid & 63, wave = tid >> 6;
  int mq = lane & 15, quad = lane >> 4;
  int wm = wave * 32;

  // Q fragments held in registers (per-lane MFMA A-fragment, loaded once)
  half8 aq[2][4];
#pragma unroll
  for (int rt = 0; rt < 2; ++rt)
#pragma unroll
    for (int ks = 0; ks < 4; ++ks)
      aq[rt][ks] = *(const half8*)(qh + (size_t)(i0 + wm + rt * 16 + mq) * 2048 + h * 128 + ks * 32 + quad * 8);

  // per-LANE running stats over this lane's j-columns only; merged across mq at the end
  float runm[2][4], runl[2][4];
#pragma unroll
  for (int rt = 0; rt < 2; ++rt)
#pragma unroll
    for (int r = 0; r < 4; ++r) { runm[rt][r] = -INFINITY; runl[rt][r] = 0.f; }

  int nblk = ib + 1;
  int jb_lo = (sp * nblk) / SPLIT;
  int jb_hi = ((sp + 1) * nblk) / SPLIT;
  for (int jb = jb_lo; jb < jb_hi; ++jb) {
    int j0 = jb * 128;
    __syncthreads();
#pragma unroll
    for (int u = 0; u < 8; ++u) {
      int unit = u * 256 + tid;
      int r = unit >> 4, c8 = (unit & 15) * 8;
      *(half8*)&Ks[r][c8] = *(const half8*)(kh + (size_t)(j0 + r) * 512 + kvh * 128 + c8);
    }
    __syncthreads();

    f32x4 acc[2][8] = {};
#pragma unroll
    for (int ks = 0; ks < 4; ++ks) {
      half8 bf[8];
#pragma unroll
      for (int ct = 0; ct < 8; ++ct) bf[ct] = *(const half8*)&Ks[ct * 16 + mq][ks * 32 + quad * 8];
#pragma unroll
      for (int rt = 0; rt < 2; ++rt)
#pragma unroll
        for (int ct = 0; ct < 8; ++ct)
          acc[rt][ct] = __builtin_amdgcn_mfma_f32_16x16x32_f16(aq[rt][ks], bf[ct], acc[rt][ct], 0, 0, 0);
    }

#pragma unroll
    for (int rt = 0; rt < 2; ++rt) {
      int rbase = i0 + wm + rt * 16 + quad * 4;
#pragma unroll
      for (int ct = 0; ct < 8; ++ct) {
        int j = j0 + ct * 16 + mq;
#pragma unroll
        for (int r = 0; r < 4; ++r) {
          float s = acc[rt][ct][r] * SCALE;
          if (j > rbase + r) s = -INFINITY;
          acc[rt][ct][r] = s;
        }
      }
#pragma unroll
      for (int r = 0; r < 4; ++r) {
        float v = acc[rt][0][r];
#pragma unroll
        for (int ct = 1; ct < 8; ++ct) v = fmaxf(v, acc[rt][ct][r]);
        float nm = fmaxf(runm[rt][r], v);
        float sn = (nm == -INFINITY) ? 0.f : nm;
        float alpha = (runm[rt][r] == -INFINITY) ? 0.f : __expf(runm[rt][r] - nm);
        float ps = 0.f;
#pragma unroll
        for (int ct = 0; ct < 8; ++ct) {
          float x = acc[rt][ct][r];
          ps += (x == -INFINITY) ? 0.f : __expf(x - sn);
        }
        runl[rt][r] = runl[rt][r] * alpha + ps;
        runm[rt][r] = nm;
      }
    }
  }

  // cross-lane (mq) merge of (m,l), once
#pragma unroll
  for (int rt = 0; rt < 2; ++rt)
#pragma unroll
    for (int r = 0; r < 4; ++r) {
      float m = runm[rt][r], l = runl[rt][r];
      for (int off = 1; off < 16; off <<= 1) {
        float om = __shfl_xor(m, off, 64);
        float ol = __shfl_xor(l, off, 64);
        float nm = fmaxf(m, om);
        float a = (m  == -INFINITY) ? 0.f : __expf(m - nm);
        float b = (om == -INFINITY) ? 0.f : __expf(om - nm);
        l = l * a + ol * b;
        m = nm;
      }
      runm[rt][r] = m; runl[rt][r] = l;
    }

  if (mq == 0) {
#pragma unroll
    for (int rt = 0; rt < 2; ++rt)
#pragma unroll
      for (int r = 0; r < 4; ++r) {
        int i = i0 + wm + rt * 16 + quad * 4 + r;
        rowmP[sp * (NH * SEQ) + h * SEQ + i] = runm[rt][r];
        rowlP[sp * (NH * SEQ) + h * SEQ + i] = runl[rt][r];
      }
  }
}

// ---------- merge split row stats ----------
__global__ void mergestats(const float* __restrict__ rowmP, const float* __restrict__ rowlP,
                           float* __restrict__ rowm, float* __restrict__ rowl) {
  int i = blockIdx.x * 256 + threadIdx.x;
  if (i >= NH * SEQ) return;
  float m = -INFINITY;
#pragma unroll
  for (int s = 0; s < SPLIT; ++s) m = fmaxf(m, rowmP[s * (NH * SEQ) + i]);
  float l = 0.f;
#pragma unroll
  for (int s = 0; s < SPLIT; ++s) {
    float ls = rowlP[s * (NH * SEQ) + i];
    if (ls > 0.f) l += ls * __expf(rowmP[s * (NH * SEQ) + i] - m);
  }
  rowm[i] = m; rowl[i] = l;
}

// ---------- S2: colsum[h][j] = sum_i exp(s_ij - m_i)/l_i, Q streamed, i-split ----------
__global__ __launch_bounds__(256) void flashcolsum(
    const _Float16* __restrict__ qh, const _Float16* __restrict__ kh,
    const float* __restrict__ rowm, const float* __restrict__ rowl,
    float* __restrict__ colsumP)
{
  int sp = blockIdx.x;                    // i-split 0..SPLIT-1
  int jb = blockIdx.y;
  int j0 = jb * 128, h = blockIdx.z, kvh = h >> 2;
  __shared__ _Float16 Ks[128][136];
  __shared__ float colred[4][128];
  int tid = threadIdx.x, lane = tid & 63, wave = tid >> 6;
  int mq = lane & 15, quad = lane >> 4;
  int wm = wave * 32;

#pragma unroll
  for (int u = 0; u < 8; ++u) {
    int unit = u * 256 + tid;
    int r = unit >> 4, c8 = (unit & 15) * 8;
    *(half8*)&Ks[r][c8] = *(const half8*)(kh + (size_t)(j0 + r) * 512 + kvh * 128 + c8);
  }
  __syncthreads();

  float colacc[8] = {};
  int n = SEQ / 128 - jb;
  int ib_lo = jb + (sp * n) / SPLIT;
  int ib_hi = jb + ((sp + 1) * n) / SPLIT;
  for (int ib = ib_lo; ib < ib_hi; ++ib) {
    int i0 = ib * 128;

    f32x4 acc[2][8] = {};
#pragma unroll
    for (int ks = 0; ks < 4; ++ks) {
      half8 af[2], bf[8];
#pragma unroll
      for (int rt = 0; rt < 2; ++rt)
        af[rt] = *(const half8*)(qh + (size_t)(i0 + wm + rt * 16 + mq) * 2048 + h * 128 + ks * 32 + quad * 8);
#pragma unroll
      for (int ct = 0; ct < 8; ++ct) bf[ct] = *(const half8*)&Ks[ct * 16 + mq][ks * 32 + quad * 8];
#pragma unroll
      for (int rt = 0; rt < 2; ++rt)
#pragma unroll
        for (int ct = 0; ct < 8; ++ct)
          acc[rt][ct] = __builtin_amdgcn_mfma_f32_16x16x32_f16(af[rt], bf[ct], acc[rt][ct], 0, 0, 0);
    }

#pragma unroll
    for (int rt = 0; rt < 2; ++rt) {
      int rbase = i0 + wm + rt * 16 + quad * 4;
      float rm[4], ri[4];
#pragma unroll
      for (int r = 0; r < 4; ++r) {
        rm[r] = rowm[h * SEQ + rbase + r];
        ri[r] = 1.f / rowl[h * SEQ + rbase + r];
      }
#pragma unroll
      for (int ct = 0; ct < 8; ++ct) {
        int j = j0 + ct * 16 + mq;
        float cp = 0.f;
#pragma unroll
        for (int r = 0; r < 4; ++r) {
          if (j <= rbase + r)
            cp += __expf(acc[rt][ct][r] * SCALE - rm[r]) * ri[r];
        }
        colacc[ct] += cp;
      }
    }
  }
#pragma unroll
  for (int ct = 0; ct < 8; ++ct) {
    float v = colacc[ct];
    v += __shfl_xor(v, 16, 64);
    v += __shfl_xor(v, 32, 64);
    colacc[ct] = v;
  }
  __syncthreads();
  if (quad == 0) {
#pragma unroll
    for (int ct = 0; ct < 8; ++ct) colred[wave][ct * 16 + mq] = colacc[ct];
  }
  __syncthreads();
  if (tid < 128)
    colsumP[sp * (NH * SEQ) + h * SEQ + j0 + tid] =
        colred[0][tid] + colred[1][tid] + colred[2][tid] + colred[3][tid];
}

// ---------- top-HEAVY per head via radix select (sums the colsum partials) ----------
__global__ __launch_bounds__(256) void topk_radix(const float* __restrict__ colsumP,
                                                  int* __restrict__ hidx) {
  int h = blockIdx.x, t = threadIdx.x;
  __shared__ unsigned vals[SEQ];
  __shared__ int hist[256];
  __shared__ int scanbuf[256];
  __shared__ unsigned s_prefix;
  __shared__ int s_k;

  for (int j = t; j < SEQ; j += 256) {
    float cs = 0.f;
#pragma unroll
    for (int s = 0; s < SPLIT; ++s) cs += colsumP[s * (NH * SEQ) + h * SEQ + j];
    vals[j] = __float_as_uint(cs);
  }

  unsigned prefix = 0, maskFixed = 0;
  int k = HEAVY;
  for (int pass = 0; pass < 4; ++pass) {
    int shift = 24 - pass * 8;
    hist[t] = 0;
    __syncthreads();
    for (int j = t; j < SEQ; j += 256) {
      unsigned v = vals[j];
      if ((v & maskFixed) == prefix) atomicAdd(&hist[(v >> shift) & 255], 1);
    }
    __syncthreads();
    if (t == 0) {
      int c = 0, d = 255;
      for (; d > 0; --d) {
        if (c + hist[d] >= k) break;
        c += hist[d];
      }
      s_k = k - c;
      s_prefix = prefix | ((unsigned)d << shift);
    }
    __syncthreads();
    prefix = s_prefix;
    k = s_k;
    maskFixed |= (0xFFu << shift);
    __syncthreads();
  }
  unsigned T = prefix;
  int tieNeed = k;

  int base = t * 8;
  int cG = 0, cT = 0;
#pragma unroll
  for (int u = 0; u < 8; ++u) {
    unsigned v = vals[base + u];
    if (v > T) cG++;
    else if (v == T) cT++;
  }
  scanbuf[t] = cG; __syncthreads();
  for (int off = 1; off < 256; off <<= 1) {
    int x = (t >= off) ? scanbuf[t - off] : 0;
    __syncthreads();
    scanbuf[t] += x;
    __syncthreads();
  }
  int exG = scanbuf[t] - cG;
  int totG = scanbuf[255];
  __syncthreads();
  scanbuf[t] = cT; __syncthreads();
  for (int off = 1; off < 256; off <<= 1) {
    int x = (t >= off) ? scanbuf[t - off] : 0;
    __syncthreads();
    scanbuf[t] += x;
    __syncthreads();
  }
  int exT = scanbuf[t] - cT;

  int slotG = exG;
  int slotT = totG + exT;
#pragma unroll
  for (int u = 0; u < 8; ++u) {
    unsigned v = vals[base + u];
    if (v > T) {
      hidx[h * HEAVY + slotG] = base + u;
      slotG++;
    } else if (v == T) {
      if (slotT < totG + tieNeed) hidx[h * HEAVY + slotT] = base + u;
      slotT++;
    }
  }
}

// ---------- attn3: sparse flash attention, 64 Q-rows / 256 threads per block ----------
__global__ __launch_bounds__(256) void attn3(
    const _Float16* __restrict__ qh, const _Float16* __restrict__ kh,
    const _Float16* __restrict__ vh, const int* __restrict__ hidx,
    _Float16* __restrict__ ctx)
{
  constexpr int TB = 64;
  int i0 = blockIdx.x * 64, h = blockIdx.y, kvh = h >> 2;
  __shared__ _Float16 QP[64][136];        // Q staging; reused as P
  __shared__ _Float16 KVu[9216];          // union: K[64][136] / VT[128][72]
  __shared__ int shx[HEAVY];
  int tid = threadIdx.x, lane = tid & 63, wave = tid >> 6;
  int mq = lane & 15, quad = lane >> 4;
  int wm = wave * 16;

  _Float16 (*Ks)[136] = (_Float16(*)[136])KVu;
  _Float16 (*Vs)[72]  = (_Float16(*)[72])KVu;

#pragma unroll
  for (int u = 0; u < 4; ++u) {
    int unit = u * 256 + tid;
    int r = unit >> 4, c8 = (unit & 15) * 8;
    *(half8*)&QP[r][c8] = *(const half8*)(qh + (size_t)(i0 + r) * 2048 + h * 128 + c8);
  }
  for (int e = tid; e < HEAVY; e += 256) shx[e] = hidx[h * HEAVY + e];
  __syncthreads();

  half8 aq[4];
#pragma unroll
  for (int ks = 0; ks < 4; ++ks) aq[ks] = *(const half8*)&QP[wm + mq][ks * 32 + quad * 8];

  float runm[4], runl[4];
#pragma unroll
  for (int r = 0; r < 4; ++r) { runm[r] = -INFINITY; runl[r] = 0.f; }
  f32x4 acc_o[8] = {};

  int tb_lo = max(0, i0 - RECENT) >> 6;
  int tb_hi = (i0 + 63) >> 6;
  int nband = tb_hi - tb_lo + 1;
  int nheavy = (i0 + 63 > RECENT) ? ((HEAVY + TB - 1) / TB) : 0;
  int ntiles = nband + nheavy;

  for (int tt = 0; tt < ntiles; ++tt) {
    bool isheavy = tt >= nband;
    int j0 = isheavy ? 0 : (tb_lo + tt) * TB;
    int e0 = isheavy ? (tt - nband) * TB : 0;

    // stage K tile (64 cols x 128 dims): lanes write 256B contiguous -> conflict-free
#pragma unroll
    for (int u = 0; u < 4; ++u) {
      int unit = u * 256 + tid;
      int c = unit >> 4, d8 = (unit & 15) * 8;
      int jabs;
      if (!isheavy) jabs = j0 + c;
      else { int e = e0 + c; jabs = (e < HEAVY) ? shx[e] : 0; }
      *(half8*)&Ks[c][d8] = *(const half8*)(kh + (size_t)jabs * 512 + kvh * 128 + d8);
    }
    int jreg[4];
#pragma unroll
    for (int ct = 0; ct < 4; ++ct) {
      int c = ct * 16 + mq;
      if (!isheavy) jreg[ct] = j0 + c;
      else { int e = e0 + c; jreg[ct] = (e < HEAVY) ? shx[e] : (1 << 28); }
    }
    __syncthreads();

    // S = Q K^T
    f32x4 s[4] = {};
#pragma unroll
    for (int ks = 0; ks < 4; ++ks) {
      half8 bf[4];
#pragma unroll
      for (int ct = 0; ct < 4; ++ct) bf[ct] = *(const half8*)&Ks[ct * 16 + mq][ks * 32 + quad * 8];
#pragma unroll
      for (int ct = 0; ct < 4; ++ct)
        s[ct] = __builtin_amdgcn_mfma_f32_16x16x32_f16(aq[ks], bf[ct], s[ct], 0, 0, 0);
    }

    // mask + online softmax
    float p[4][4];
#pragma unroll
    for (int r = 0; r < 4; ++r) {
      int i = i0 + wm + quad * 4 + r;
      float sv[4];
      float mx = -INFINITY;
#pragma unroll
      for (int ct = 0; ct < 4; ++ct) {
        int j = jreg[ct];
        bool ok = isheavy ? (j < i - RECENT) : (j >= i - RECENT && j <= i);
        float x = ok ? s[ct][r] * SCALE : -INFINITY;
        sv[ct] = x;
        mx = fmaxf(mx, x);
      }
      for (int off = 1; off < 16; off <<= 1) mx = fmaxf(mx, __shfl_xor(mx, off, 64));
      float nm = fmaxf(runm[r], mx);
      float sn = (nm == -INFINITY) ? 0.f : nm;
      float alpha = (runm[r] == -INFINITY) ? 0.f : __expf(runm[r] - nm);
      float ps = 0.f;
#pragma unroll
      for (int ct = 0; ct < 4; ++ct) {
        float pe = (sv[ct] == -INFINITY) ? 0.f : __expf(sv[ct] - sn);
        p[ct][r] = pe;
        ps += pe;
      }
      for (int off = 1; off < 16; off <<= 1) ps += __shfl_xor(ps, off, 64);
      runl[r] = runl[r] * alpha + ps;
      runm[r] = nm;
#pragma unroll
      for (int ct = 0; ct < 8; ++ct) acc_o[ct][r] *= alpha;
    }
    __syncthreads();   // all waves done reading Ks

    // stage V^T (overwrites K region): c = lane-consecutive columns, conflict-free
#pragma unroll
    for (int u = 0; u < 4; ++u) {
      int unit = u * 256 + tid;
      int c = unit & 63;           // KV column (lane-consecutive)
      int d8 = (unit >> 6) * 8;    // dim octet 0..120
      int jabs;
      if (!isheavy) jabs = j0 + c;
      else { int e = e0 + c; jabs = (e < HEAVY) ? shx[e] : 0; }
      half8 v8 = *(const half8*)(vh + (size_t)jabs * 512 + kvh * 128 + d8);
#pragma unroll
      for (int e2 = 0; e2 < 8; ++e2) Vs[d8 + e2][c] = v8[e2];
    }
#pragma unroll
    for (int ct = 0; ct < 4; ++ct)
#pragma unroll
      for (int r = 0; r < 4; ++r)
        QP[wm + quad * 4 + r][ct * 16 + mq] = (_Float16)p[ct][r];
    __syncthreads();

    // O += P V
#pragma unroll
    for (int ks = 0; ks < 2; ++ks) {
      half8 ap = *(const half8*)&QP[wm + mq][ks * 32 + quad * 8];
      half8 bf[8];
#pragma unroll
      for (int ct = 0; ct < 8; ++ct) bf[ct] = *(const half8*)&Vs[ct * 16 + mq][ks * 32 + quad * 8];
#pragma unroll
      for (int ct = 0; ct < 8; ++ct)
        acc_o[ct] = __builtin_amdgcn_mfma_f32_16x16x32_f16(ap, bf[ct], acc_o[ct], 0, 0, 0);
    }
    __syncthreads();   // done with Vs/QP before next tile staging
  }

  float inv[4];
#pragma unroll
  for (int r = 0; r < 4; ++r) inv[r] = (runl[r] > 0.f) ? 1.f / runl[r] : 0.f;
#pragma unroll
  for (int ct = 0; ct < 8; ++ct) {
    int d = ct * 16 + mq;
#pragma unroll
    for (int r = 0; r < 4; ++r) {
      int i = i0 + wm + quad * 4 + r;
      ctx[(size_t)i * 2048 + h * 128 + d] = (_Float16)(acc_o[ct][r] * inv[r]);
    }
  }
}

// ---------- launch ----------
extern "C" void kernel_launch(void* const* d_in, const int* in_sizes, int n_in,
                              void* d_out, int out_size, void* d_ws, size_t ws_size,
                              hipStream_t stream) {
  const float* hs   = (const float*)d_in[0];
  const float* cosb = (const float*)d_in[1];
  const float* sinb = (const float*)d_in[2];
  const float* Wq = (const float*)d_in[4];
  const float* bq = (const float*)d_in[5];
  const float* Wk = (const float*)d_in[6];
  const float* bk = (const float*)d_in[7];
  const float* Wv = (const float*)d_in[8];
  const float* bv = (const float*)d_in[9];
  const float* Wo = (const float*)d_in[10];
  float* out = (float*)d_out;

  char* ws = (char*)d_ws;
  // lifetimes:  WT(12M)@0 -> [ctxH(8M)@0 + stats@9M];  qkv(24M)@12M -> [WoT(8M)@12M + woP1(16M)@20M];
  //             hsH(8M)@36M -> kh+vh(4M)@36M;  qh(8M)@44M (biasqkv@44M dead before qh written);
  //             qkvP1(24M)@52M only if ws_size allows.
  _Float16* WT   = (_Float16*)ws;                       // [3072][2048] f16 12 MB @0
  _Float16* ctxH = (_Float16*)ws;                       // 8 MB @0 (after WT dead)
  float* rowmP   = (float*)(ws + (9u << 20));           // @9M (after WT dead): SPLIT x NH*SEQ
  float* rowlP   = rowmP + SPLIT * NH * SEQ;
  float* rowm    = rowlP + SPLIT * NH * SEQ;
  float* rowl    = rowm + NH * SEQ;
  float* colsumP = rowl + NH * SEQ;                     // SPLIT x NH*SEQ
  int*   hidx    = (int*)(colsumP + SPLIT * NH * SEQ);
  float* qkv     = (float*)(ws + (12u << 20));          // [2048][3072] f32 24 MB @12M
  _Float16* WoT  = (_Float16*)(ws + (12u << 20));       // 8 MB @12M (after qkv dead)
  float* woP1    = (float*)(ws + (20u << 20));          // 16 MB @20M (after qkv dead)
  _Float16* hsH  = (_Float16*)(ws + (36u << 20));       // 8 MB @36M
  _Float16* kh   = (_Float16*)(ws + (36u << 20));       // 2 MB @36M (after hsH dead)
  _Float16* vh   = (_Float16*)(ws + (38u << 20));       // 2 MB @38M
  _Float16* qh   = (_Float16*)(ws + (44u << 20));       // 8 MB @44M
  float* biasqkv = (float*)(ws + (44u << 20));          // 12 KB @44M (dead before qh written)
  bool splitqkv  = ws_size >= ((size_t)76 << 20);
  float* qkvP1   = (float*)(ws + (52u << 20));          // 24 MB @52M (only if splitqkv)

  cvt_h<<<(SEQ * 2048 / 4 + 255) / 256, 256, 0, stream>>>(hs, hsH, SEQ * 2048);
  transpose_qkv<<<dim3(2048 / 64, 2048 / 64, 3), 256, 0, stream>>>(Wq, Wk, Wv, WT);
  concat_bias<<<12, 256, 0, stream>>>(bq, bk, bv, biasqkv);

  // fused QKV projection: split-K=2 into separate f32 partials when workspace allows
  if (splitqkv)
    gemm_h<<<dim3(3072 / 128, 2048 / 128, 2), 256, 0, stream>>>(hsH, WT, biasqkv, qkv, qkvP1,
                                                                SEQ, 3072, 2048);
  else
    gemm_h<<<dim3(3072 / 128, 2048 / 128, 1), 256, 0, stream>>>(hsH, WT, biasqkv, qkv, nullptr,
                                                                SEQ, 3072, 2048);

  // RoPE + f16 emit (qh/kh/vh), summing partials; qkv and hsH dead afterwards
  int np = SEQ * 16 * 64 + SEQ * 4 * 64 + SEQ * 4 * 128;
  postproc<<<(np + 255) / 256, 256, 0, stream>>>(qkv, splitqkv ? qkvP1 : nullptr,
                                                 cosb, sinb, qh, kh, vh);

  // Wo transpose into qkv's (now dead) space
  transpose_h<<<dim3(2048 / 64, 2048 / 64), 256, 0, stream>>>(Wo, WoT, 2048, 2048);

  flashstats<<<dim3(SPLIT, SEQ / 128, NH), 256, 0, stream>>>(qh, kh, rowmP, rowlP);
  mergestats<<<(NH * SEQ + 255) / 256, 256, 0, stream>>>(rowmP, rowlP, rowm, rowl);
  flashcolsum<<<dim3(SPLIT, SEQ / 128, NH), 256, 0, stream>>>(qh, kh, rowm, rowl, colsumP);
  topk_radix<<<NH, 256, 0, stream>>>(colsumP, hidx);
  attn3<<<dim3(SEQ / 64, NH), 256, 0, stream>>>(qh, kh, vh, hidx, ctxH);

  // output projection: split-K=2, partial 0 straight into out, partial 1 added after
  gemm_h<<<dim3(2048 / 128, 2048 / 128, 2), 256, 0, stream>>>(ctxH, WoT, (const float*)nullptr,
                                                              out, woP1, SEQ, 2048, 2048);
  addout<<<(SEQ * 2048 / 4 + 255) / 256, 256, 0, stream>>>(out, woP1, SEQ * 2048);
}

// Round 4
// 409.777 us; speedup vs baseline: 1.1305x; 1.0298x over previous
//
#include <hip/hip_runtime.h>
#include <hip/hip_bf16.h>
#include <math.h>

constexpr int SEQ    = 2048;
constexpr int NH     = 16;
constexpr int HEAVY  = 204;   // int(0.1*2048)
constexpr int RECENT = 204;   // int(0.1*2048)
constexpr int SPLIT  = 4;     // flash stats/colsum split factor
constexpr float SCALE = 0.08838834764831845f; // 128^-0.5

typedef _Float16 half8 __attribute__((ext_vector_type(8)));
typedef float f32x4 __attribute__((ext_vector_type(4)));

typedef __attribute__((address_space(1))) const void cg_void;
typedef __attribute__((address_space(3))) void l_void;

// ---------- f32 -> f16 convert ----------
__global__ void cvt_h(const float* __restrict__ src, _Float16* __restrict__ dst, int n) {
  int i = (blockIdx.x * 256 + threadIdx.x) * 4;
  if (i + 3 < n) {
    float4 v = *(const float4*)(src + i);
    dst[i] = (_Float16)v.x; dst[i+1] = (_Float16)v.y;
    dst[i+2] = (_Float16)v.z; dst[i+3] = (_Float16)v.w;
  } else {
    for (int u = i; u < n; ++u) dst[u] = (_Float16)src[u];
  }
}

// ---------- transpose + convert: W f32 [K][N] -> WT f16 [N][K] ----------
__global__ __launch_bounds__(256) void transpose_h(
    const float* __restrict__ W, _Float16* __restrict__ WT, int K, int N) {
  __shared__ float T[64][65];
  int c = threadIdx.x & 63, rq = threadIdx.x >> 6;
  int n0 = blockIdx.x * 64, k0 = blockIdx.y * 64;
#pragma unroll
  for (int u = 0; u < 16; ++u) {
    int r = rq * 16 + u;
    T[r][c] = W[(size_t)(k0 + r) * N + n0 + c];
  }
  __syncthreads();
#pragma unroll
  for (int u = 0; u < 16; ++u) {
    int r = rq * 16 + u;
    WT[(size_t)(n0 + r) * K + k0 + c] = (_Float16)T[c][r];
  }
}

// ---------- batched transpose of Wq/Wk/Wv into WT ----------
__global__ __launch_bounds__(256) void transpose_qkv(
    const float* __restrict__ Wq, const float* __restrict__ Wk,
    const float* __restrict__ Wv, _Float16* __restrict__ WT) {
  int z = blockIdx.z;
  const float* W = (z == 0) ? Wq : ((z == 1) ? Wk : Wv);
  int N = (z == 0) ? 2048 : 512;
  size_t dstoff = (z == 0) ? 0 : ((z == 1) ? (size_t)2048 * 2048 : (size_t)2560 * 2048);
  int n0 = blockIdx.x * 64, k0 = blockIdx.y * 64;
  if (n0 >= N) return;
  __shared__ float T[64][65];
  int c = threadIdx.x & 63, rq = threadIdx.x >> 6;
#pragma unroll
  for (int u = 0; u < 16; ++u) {
    int r = rq * 16 + u;
    T[r][c] = W[(size_t)(k0 + r) * N + n0 + c];
  }
  __syncthreads();
#pragma unroll
  for (int u = 0; u < 16; ++u) {
    int r = rq * 16 + u;
    WT[dstoff + (size_t)(n0 + r) * 2048 + k0 + c] = (_Float16)T[c][r];
  }
}

// ---------- concat bias [bq|bk|bv] -> 3072 floats ----------
__global__ void concat_bias(const float* __restrict__ bq, const float* __restrict__ bk,
                            const float* __restrict__ bv, float* __restrict__ b) {
  int i = blockIdx.x * 256 + threadIdx.x;
  if (i < 2048) b[i] = bq[i];
  else if (i < 2560) b[i] = bk[i - 2048];
  else if (i < 3072) b[i] = bv[i - 2560];
}

// ---------- MFMA f16 GEMM, m97 structure, split-K via gridDim.z into SEPARATE buffers ----------
// LDS: linear [128][32] halfs, XOR-swizzled k-slots (pre-swizzled global src + swizzled read).
__global__ __launch_bounds__(256) void gemm_h(
    const _Float16* __restrict__ A, const _Float16* __restrict__ BT,
    const float* __restrict__ bias, float* __restrict__ C0, float* __restrict__ C1,
    int M, int N, int K)
{
  __shared__ _Float16 As[128 * 32];
  __shared__ _Float16 Bs[128 * 32];
  int tid = threadIdx.x, lane = tid & 63, wave = tid >> 6;
  int wm = (wave & 1) * 64, wn = (wave >> 1) * 64;
  int m0 = blockIdx.y * 128, n0 = blockIdx.x * 128;
  int mq = lane & 15, quad = lane >> 4;
  int kz = blockIdx.z, nz = gridDim.z;
  int kchunk = K / nz;
  int kbeg = kz * kchunk, kend = kbeg + kchunk;
  float* C = kz ? C1 : C0;

  f32x4 acc[4][4] = {};

  // staging: wave w covers rows [w*32, w*32+32), two 16-row segments of 1KB
  int rstage = wave * 32 + (lane >> 2);
  int qs = ((lane & 3) ^ ((lane >> 3) & 3)) * 8;   // pre-swizzled k-slot (halfs)
  const _Float16* gA = A  + (size_t)(m0 + rstage) * K + qs;
  const _Float16* gB = BT + (size_t)(n0 + rstage) * K + qs;
  _Float16* lA0 = &As[(wave * 32) * 32];
  _Float16* lA1 = &As[(wave * 32 + 16) * 32];
  _Float16* lB0 = &Bs[(wave * 32) * 32];
  _Float16* lB1 = &Bs[(wave * 32 + 16) * 32];

  int sw = (quad ^ ((mq >> 1) & 3)) * 8;           // read-side swizzled slot (halfs)

  for (int k0 = kbeg; k0 < kend; k0 += 32) {
    __builtin_amdgcn_global_load_lds((cg_void*)(gA + k0),                   (l_void*)lA0, 16, 0, 0);
    __builtin_amdgcn_global_load_lds((cg_void*)(gA + (size_t)16 * K + k0),  (l_void*)lA1, 16, 0, 0);
    __builtin_amdgcn_global_load_lds((cg_void*)(gB + k0),                   (l_void*)lB0, 16, 0, 0);
    __builtin_amdgcn_global_load_lds((cg_void*)(gB + (size_t)16 * K + k0),  (l_void*)lB1, 16, 0, 0);
    __syncthreads();
    half8 af[4], bf[4];
#pragma unroll
    for (int t4 = 0; t4 < 4; ++t4) {
      af[t4] = *(const half8*)&As[(wm + t4 * 16 + mq) * 32 + sw];
      bf[t4] = *(const half8*)&Bs[(wn + t4 * 16 + mq) * 32 + sw];
    }
#pragma unroll
    for (int mt = 0; mt < 4; ++mt)
#pragma unroll
      for (int nt = 0; nt < 4; ++nt)
        acc[mt][nt] = __builtin_amdgcn_mfma_f32_16x16x32_f16(af[mt], bf[nt], acc[mt][nt], 0, 0, 0);
    __syncthreads();
  }

#pragma unroll
  for (int mt = 0; mt < 4; ++mt)
#pragma unroll
    for (int nt = 0; nt < 4; ++nt) {
      int n = n0 + wn + nt * 16 + mq;
      float bb = (bias && kz == 0) ? bias[n] : 0.f;
#pragma unroll
      for (int r = 0; r < 4; ++r) {
        int m = m0 + wm + mt * 16 + quad * 4 + r;
        C[(size_t)m * N + n] = acc[mt][nt][r] + bb;
      }
    }
}

// ---------- add partial into out ----------
__global__ void addout(float* __restrict__ out, const float* __restrict__ p1, int n) {
  int i = (blockIdx.x * 256 + threadIdx.x) * 4;
  if (i + 3 < n) {
    float4 a = *(const float4*)(out + i);
    float4 b = *(const float4*)(p1 + i);
    a.x += b.x; a.y += b.y; a.z += b.z; a.w += b.w;
    *(float4*)(out + i) = a;
  } else {
    for (int u = i; u < n; ++u) out[u] += p1[u];
  }
}

// ---------- postproc: qkv partials f32 [s][3072] -> RoPE'd qh/kh + vh (all f16) ----------
__global__ void postproc(const float* __restrict__ qkv, const float* __restrict__ qkv1,
                         const float* __restrict__ cosb, const float* __restrict__ sinb,
                         _Float16* __restrict__ qh, _Float16* __restrict__ kh,
                         _Float16* __restrict__ vh) {
  int idx = blockIdx.x * 256 + threadIdx.x;
  const int NQ = SEQ * 16 * 64, NK = SEQ * 4 * 64, NV = SEQ * 4 * 128;
  bool sp = (qkv1 != nullptr);
  if (idx < NQ) {
    int d = idx & 63; int rest = idx >> 6; int h = rest & 15; int s = rest >> 4;
    size_t o = (size_t)s * 3072 + h * 128;
    float x1 = qkv[o + d]      + (sp ? qkv1[o + d] : 0.f);
    float x2 = qkv[o + d + 64] + (sp ? qkv1[o + d + 64] : 0.f);
    float c1 = cosb[(size_t)s * 128 + d], c2 = cosb[(size_t)s * 128 + d + 64];
    float s1 = sinb[(size_t)s * 128 + d], s2 = sinb[(size_t)s * 128 + d + 64];
    qh[(size_t)s * 2048 + h * 128 + d]      = (_Float16)(x1 * c1 - x2 * s1);
    qh[(size_t)s * 2048 + h * 128 + d + 64] = (_Float16)(x2 * c2 + x1 * s2);
  } else if (idx < NQ + NK) {
    int r = idx - NQ;
    int d = r & 63; int rest = r >> 6; int h = rest & 3; int s = rest >> 2;
    size_t o = (size_t)s * 3072 + 2048 + h * 128;
    float x1 = qkv[o + d]      + (sp ? qkv1[o + d] : 0.f);
    float x2 = qkv[o + d + 64] + (sp ? qkv1[o + d + 64] : 0.f);
    float c1 = cosb[(size_t)s * 128 + d], c2 = cosb[(size_t)s * 128 + d + 64];
    float s1 = sinb[(size_t)s * 128 + d], s2 = sinb[(size_t)s * 128 + d + 64];
    kh[(size_t)s * 512 + h * 128 + d]      = (_Float16)(x1 * c1 - x2 * s1);
    kh[(size_t)s * 512 + h * 128 + d + 64] = (_Float16)(x2 * c2 + x1 * s2);
  } else if (idx < NQ + NK + NV) {
    int r = idx - NQ - NK;
    int d = r & 127; int rest = r >> 7; int h = rest & 3; int s = rest >> 2;
    size_t o = (size_t)s * 3072 + 2560 + h * 128 + d;
    float x = qkv[o] + (sp ? qkv1[o] : 0.f);
    vh[(size_t)s * 512 + h * 128 + d] = (_Float16)x;
  }
}

// ---------- S1: flash row stats (m_i, l_i), Q in registers, per-lane online, j-split ----------
__global__ __launch_bounds__(256) void flashstats(
    const _Float16* __restrict__ qh, const _Float16* __restrict__ kh,
    float* __restrict__ rowmP, float* __restrict__ rowlP)
{
  int sp = blockIdx.x;                    // j-split 0..SPLIT-1
  int ib = blockIdx.y;
  int i0 = ib * 128, h = blockIdx.z, kvh = h >> 2;
  __shared__ _Float16 Ks[128][136];
  int tid = threadIdx.x, lane = tid & 63, wave = tid >> 6;
  int mq = lane & 15, quad = lane >> 4;
  int wm = wave * 32;

  // Q fragments held in registers (per-lane MFMA A-fragment, loaded once)
  half8 aq[2][4];
#pragma unroll
  for (int rt = 0; rt < 2; ++rt)
#pragma unroll
    for (int ks = 0; ks < 4; ++ks)
      aq[rt][ks] = *(const half8*)(qh + (size_t)(i0 + wm + rt * 16 + mq) * 2048 + h * 128 + ks * 32 + quad * 8);

  // per-LANE running stats over this lane's j-columns only; merged across mq at the end
  float runm[2][4], runl[2][4];
#pragma unroll
  for (int rt = 0; rt < 2; ++rt)
#pragma unroll
    for (int r = 0; r < 4; ++r) { runm[rt][r] = -INFINITY; runl[rt][r] = 0.f; }

  int nblk = ib + 1;
  int jb_lo = (sp * nblk) / SPLIT;
  int jb_hi = ((sp + 1) * nblk) / SPLIT;
  for (int jb = jb_lo; jb < jb_hi; ++jb) {
    int j0 = jb * 128;
    __syncthreads();
#pragma unroll
    for (int u = 0; u < 8; ++u) {
      int unit = u * 256 + tid;
      int r = unit >> 4, c8 = (unit & 15) * 8;
      *(half8*)&Ks[r][c8] = *(const half8*)(kh + (size_t)(j0 + r) * 512 + kvh * 128 + c8);
    }
    __syncthreads();

    f32x4 acc[2][8] = {};
#pragma unroll
    for (int ks = 0; ks < 4; ++ks) {
      half8 bf[8];
#pragma unroll
      for (int ct = 0; ct < 8; ++ct) bf[ct] = *(const half8*)&Ks[ct * 16 + mq][ks * 32 + quad * 8];
#pragma unroll
      for (int rt = 0; rt < 2; ++rt)
#pragma unroll
        for (int ct = 0; ct < 8; ++ct)
          acc[rt][ct] = __builtin_amdgcn_mfma_f32_16x16x32_f16(aq[rt][ks], bf[ct], acc[rt][ct], 0, 0, 0);
    }

#pragma unroll
    for (int rt = 0; rt < 2; ++rt) {
      int rbase = i0 + wm + rt * 16 + quad * 4;
#pragma unroll
      for (int ct = 0; ct < 8; ++ct) {
        int j = j0 + ct * 16 + mq;
#pragma unroll
        for (int r = 0; r < 4; ++r) {
          float s = acc[rt][ct][r] * SCALE;
          if (j > rbase + r) s = -INFINITY;
          acc[rt][ct][r] = s;
        }
      }
#pragma unroll
      for (int r = 0; r < 4; ++r) {
        float v = acc[rt][0][r];
#pragma unroll
        for (int ct = 1; ct < 8; ++ct) v = fmaxf(v, acc[rt][ct][r]);
        float nm = fmaxf(runm[rt][r], v);
        float sn = (nm == -INFINITY) ? 0.f : nm;
        float alpha = (runm[rt][r] == -INFINITY) ? 0.f : __expf(runm[rt][r] - nm);
        float ps = 0.f;
#pragma unroll
        for (int ct = 0; ct < 8; ++ct) {
          float x = acc[rt][ct][r];
          ps += (x == -INFINITY) ? 0.f : __expf(x - sn);
        }
        runl[rt][r] = runl[rt][r] * alpha + ps;
        runm[rt][r] = nm;
      }
    }
  }

  // cross-lane (mq) merge of (m,l), once
#pragma unroll
  for (int rt = 0; rt < 2; ++rt)
#pragma unroll
    for (int r = 0; r < 4; ++r) {
      float m = runm[rt][r], l = runl[rt][r];
      for (int off = 1; off < 16; off <<= 1) {
        float om = __shfl_xor(m, off, 64);
        float ol = __shfl_xor(l, off, 64);
        float nm = fmaxf(m, om);
        float a = (m  == -INFINITY) ? 0.f : __expf(m - nm);
        float b = (om == -INFINITY) ? 0.f : __expf(om - nm);
        l = l * a + ol * b;
        m = nm;
      }
      runm[rt][r] = m; runl[rt][r] = l;
    }

  if (mq == 0) {
#pragma unroll
    for (int rt = 0; rt < 2; ++rt)
#pragma unroll
      for (int r = 0; r < 4; ++r) {
        int i = i0 + wm + rt * 16 + quad * 4 + r;
        rowmP[sp * (NH * SEQ) + h * SEQ + i] = runm[rt][r];
        rowlP[sp * (NH * SEQ) + h * SEQ + i] = runl[rt][r];
      }
  }
}

// ---------- merge split row stats ----------
__global__ void mergestats(const float* __restrict__ rowmP, const float* __restrict__ rowlP,
                           float* __restrict__ rowm, float* __restrict__ rowl) {
  int i = blockIdx.x * 256 + threadIdx.x;
  if (i >= NH * SEQ) return;
  float m = -INFINITY;
#pragma unroll
  for (int s = 0; s < SPLIT; ++s) m = fmaxf(m, rowmP[s * (NH * SEQ) + i]);
  float l = 0.f;
#pragma unroll
  for (int s = 0; s < SPLIT; ++s) {
    float ls = rowlP[s * (NH * SEQ) + i];
    if (ls > 0.f) l += ls * __expf(rowmP[s * (NH * SEQ) + i] - m);
  }
  rowm[i] = m; rowl[i] = l;
}

// ---------- S2: colsum[h][j] = sum_i exp(s_ij - m_i)/l_i, Q streamed, i-split ----------
__global__ __launch_bounds__(256) void flashcolsum(
    const _Float16* __restrict__ qh, const _Float16* __restrict__ kh,
    const float* __restrict__ rowm, const float* __restrict__ rowl,
    float* __restrict__ colsumP)
{
  int sp = blockIdx.x;                    // i-split 0..SPLIT-1
  int jb = blockIdx.y;
  int j0 = jb * 128, h = blockIdx.z, kvh = h >> 2;
  __shared__ _Float16 Ks[128][136];
  __shared__ float colred[4][128];
  int tid = threadIdx.x, lane = tid & 63, wave = tid >> 6;
  int mq = lane & 15, quad = lane >> 4;
  int wm = wave * 32;

#pragma unroll
  for (int u = 0; u < 8; ++u) {
    int unit = u * 256 + tid;
    int r = unit >> 4, c8 = (unit & 15) * 8;
    *(half8*)&Ks[r][c8] = *(const half8*)(kh + (size_t)(j0 + r) * 512 + kvh * 128 + c8);
  }
  __syncthreads();

  float colacc[8] = {};
  int n = SEQ / 128 - jb;
  int ib_lo = jb + (sp * n) / SPLIT;
  int ib_hi = jb + ((sp + 1) * n) / SPLIT;
  for (int ib = ib_lo; ib < ib_hi; ++ib) {
    int i0 = ib * 128;

    f32x4 acc[2][8] = {};
#pragma unroll
    for (int ks = 0; ks < 4; ++ks) {
      half8 af[2], bf[8];
#pragma unroll
      for (int rt = 0; rt < 2; ++rt)
        af[rt] = *(const half8*)(qh + (size_t)(i0 + wm + rt * 16 + mq) * 2048 + h * 128 + ks * 32 + quad * 8);
#pragma unroll
      for (int ct = 0; ct < 8; ++ct) bf[ct] = *(const half8*)&Ks[ct * 16 + mq][ks * 32 + quad * 8];
#pragma unroll
      for (int rt = 0; rt < 2; ++rt)
#pragma unroll
        for (int ct = 0; ct < 8; ++ct)
          acc[rt][ct] = __builtin_amdgcn_mfma_f32_16x16x32_f16(af[rt], bf[ct], acc[rt][ct], 0, 0, 0);
    }

#pragma unroll
    for (int rt = 0; rt < 2; ++rt) {
      int rbase = i0 + wm + rt * 16 + quad * 4;
      float rm[4], ri[4];
#pragma unroll
      for (int r = 0; r < 4; ++r) {
        rm[r] = rowm[h * SEQ + rbase + r];
        ri[r] = 1.f / rowl[h * SEQ + rbase + r];
      }
#pragma unroll
      for (int ct = 0; ct < 8; ++ct) {
        int j = j0 + ct * 16 + mq;
        float cp = 0.f;
#pragma unroll
        for (int r = 0; r < 4; ++r) {
          if (j <= rbase + r)
            cp += __expf(acc[rt][ct][r] * SCALE - rm[r]) * ri[r];
        }
        colacc[ct] += cp;
      }
    }
  }
#pragma unroll
  for (int ct = 0; ct < 8; ++ct) {
    float v = colacc[ct];
    v += __shfl_xor(v, 16, 64);
    v += __shfl_xor(v, 32, 64);
    colacc[ct] = v;
  }
  __syncthreads();
  if (quad == 0) {
#pragma unroll
    for (int ct = 0; ct < 8; ++ct) colred[wave][ct * 16 + mq] = colacc[ct];
  }
  __syncthreads();
  if (tid < 128)
    colsumP[sp * (NH * SEQ) + h * SEQ + j0 + tid] =
        colred[0][tid] + colred[1][tid] + colred[2][tid] + colred[3][tid];
}

// ---------- top-HEAVY per head via radix select (sums the colsum partials) ----------
__global__ __launch_bounds__(256) void topk_radix(const float* __restrict__ colsumP,
                                                  int* __restrict__ hidx) {
  int h = blockIdx.x, t = threadIdx.x;
  __shared__ unsigned vals[SEQ];
  __shared__ int hist[256];
  __shared__ int scanbuf[256];
  __shared__ unsigned s_prefix;
  __shared__ int s_k;

  for (int j = t; j < SEQ; j += 256) {
    float cs = 0.f;
#pragma unroll
    for (int s = 0; s < SPLIT; ++s) cs += colsumP[s * (NH * SEQ) + h * SEQ + j];
    vals[j] = __float_as_uint(cs);
  }

  unsigned prefix = 0, maskFixed = 0;
  int k = HEAVY;
  for (int pass = 0; pass < 4; ++pass) {
    int shift = 24 - pass * 8;
    hist[t] = 0;
    __syncthreads();
    for (int j = t; j < SEQ; j += 256) {
      unsigned v = vals[j];
      if ((v & maskFixed) == prefix) atomicAdd(&hist[(v >> shift) & 255], 1);
    }
    __syncthreads();
    if (t == 0) {
      int c = 0, d = 255;
      for (; d > 0; --d) {
        if (c + hist[d] >= k) break;
        c += hist[d];
      }
      s_k = k - c;
      s_prefix = prefix | ((unsigned)d << shift);
    }
    __syncthreads();
    prefix = s_prefix;
    k = s_k;
    maskFixed |= (0xFFu << shift);
    __syncthreads();
  }
  unsigned T = prefix;
  int tieNeed = k;

  int base = t * 8;
  int cG = 0, cT = 0;
#pragma unroll
  for (int u = 0; u < 8; ++u) {
    unsigned v = vals[base + u];
    if (v > T) cG++;
    else if (v == T) cT++;
  }
  scanbuf[t] = cG; __syncthreads();
  for (int off = 1; off < 256; off <<= 1) {
    int x = (t >= off) ? scanbuf[t - off] : 0;
    __syncthreads();
    scanbuf[t] += x;
    __syncthreads();
  }
  int exG = scanbuf[t] - cG;
  int totG = scanbuf[255];
  __syncthreads();
  scanbuf[t] = cT; __syncthreads();
  for (int off = 1; off < 256; off <<= 1) {
    int x = (t >= off) ? scanbuf[t - off] : 0;
    __syncthreads();
    scanbuf[t] += x;
    __syncthreads();
  }
  int exT = scanbuf[t] - cT;

  int slotG = exG;
  int slotT = totG + exT;
#pragma unroll
  for (int u = 0; u < 8; ++u) {
    unsigned v = vals[base + u];
    if (v > T) {
      hidx[h * HEAVY + slotG] = base + u;
      slotG++;
    } else if (v == T) {
      if (slotT < totG + tieNeed) hidx[h * HEAVY + slotT] = base + u;
      slotT++;
    }
  }
}

// ---------- attn3: sparse flash attention, NO online softmax ----------
// Uses precomputed full-causal row max (rowm) as the exp reference point:
// an upper bound on the masked-subset max, so P = exp(s - rowm) in (0,1],
// numerator and denominator scale identically -> O unchanged, but no
// cross-lane max, no alpha rescale, no in-loop shfl.  V is loaded to
// registers at tile start (latency hides under QK^T), 2 barriers/tile.
__global__ __launch_bounds__(256) void attn3(
    const _Float16* __restrict__ qh, const _Float16* __restrict__ kh,
    const _Float16* __restrict__ vh, const int* __restrict__ hidx,
    const float* __restrict__ rowm, _Float16* __restrict__ ctx)
{
  constexpr int TB = 64;
  int i0 = blockIdx.x * 64, h = blockIdx.y, kvh = h >> 2;
  __shared__ _Float16 Ks[64][136];        // K tile
  __shared__ _Float16 Vs[128][72];        // V^T tile
  __shared__ _Float16 Ps[64][72];         // P tile (wave-local rows)
  __shared__ int shx[HEAVY];
  int tid = threadIdx.x, lane = tid & 63, wave = tid >> 6;
  int mq = lane & 15, quad = lane >> 4;
  int wm = wave * 16;

  for (int e = tid; e < HEAVY; e += 256) shx[e] = hidx[h * HEAVY + e];

  // Q fragment + row-max reference, straight from global (per-lane)
  half8 aq[4];
#pragma unroll
  for (int ks = 0; ks < 4; ++ks)
    aq[ks] = *(const half8*)(qh + (size_t)(i0 + wm + mq) * 2048 + h * 128 + ks * 32 + quad * 8);
  float rm[4];
#pragma unroll
  for (int r = 0; r < 4; ++r) rm[r] = rowm[h * SEQ + i0 + wm + quad * 4 + r];

  float runl[4] = {0.f, 0.f, 0.f, 0.f};
  f32x4 acc_o[8] = {};
  __syncthreads();   // shx ready

  int tb_lo = max(0, i0 - RECENT) >> 6;
  int tb_hi = (i0 + 63) >> 6;
  int nband = tb_hi - tb_lo + 1;
  int nheavy = (i0 + 63 > RECENT) ? ((HEAVY + TB - 1) / TB) : 0;
  int ntiles = nband + nheavy;

  for (int tt = 0; tt < ntiles; ++tt) {
    bool isheavy = tt >= nband;
    int j0 = isheavy ? 0 : (tb_lo + tt) * TB;
    int e0 = isheavy ? (tt - nband) * TB : 0;

    // V tile -> registers (each thread: column (e0|j0)+lane, dim octets (u*4+wave)*8)
    int jv;
    if (!isheavy) jv = j0 + lane;
    else { int e = e0 + lane; jv = (e < HEAVY) ? shx[e] : 0; }
    half8 vreg[4];
#pragma unroll
    for (int u = 0; u < 4; ++u)
      vreg[u] = *(const half8*)(vh + (size_t)jv * 512 + kvh * 128 + (u * 4 + wave) * 8);

    // K tile -> LDS (64 cols x 128 dims): 16 lanes per row, 256B contiguous
#pragma unroll
    for (int u = 0; u < 4; ++u) {
      int unit = u * 256 + tid;
      int c = unit >> 4, d8 = (unit & 15) * 8;
      int jabs;
      if (!isheavy) jabs = j0 + c;
      else { int e = e0 + c; jabs = (e < HEAVY) ? shx[e] : 0; }
      *(half8*)&Ks[c][d8] = *(const half8*)(kh + (size_t)jabs * 512 + kvh * 128 + d8);
    }
    int jreg[4];
#pragma unroll
    for (int ct = 0; ct < 4; ++ct) {
      int c = ct * 16 + mq;
      if (!isheavy) jreg[ct] = j0 + c;
      else { int e = e0 + c; jreg[ct] = (e < HEAVY) ? shx[e] : (1 << 28); }
    }
    __syncthreads();   // bar1: Ks ready; prev-tile Vs reads all complete

    // S = Q K^T
    f32x4 s[4] = {};
#pragma unroll
    for (int ks = 0; ks < 4; ++ks) {
      half8 bf[4];
#pragma unroll
      for (int ct = 0; ct < 4; ++ct) bf[ct] = *(const half8*)&Ks[ct * 16 + mq][ks * 32 + quad * 8];
#pragma unroll
      for (int ct = 0; ct < 4; ++ct)
        s[ct] = __builtin_amdgcn_mfma_f32_16x16x32_f16(aq[ks], bf[ct], s[ct], 0, 0, 0);
    }

    // mask + exp against precomputed row max; per-lane partial denominator
#pragma unroll
    for (int r = 0; r < 4; ++r) {
      int i = i0 + wm + quad * 4 + r;
      float ps = 0.f;
#pragma unroll
      for (int ct = 0; ct < 4; ++ct) {
        int j = jreg[ct];
        bool ok = isheavy ? (j < i - RECENT) : (j >= i - RECENT && j <= i);
        float pe = ok ? __expf(s[ct][r] * SCALE - rm[r]) : 0.f;
        Ps[wm + quad * 4 + r][ct * 16 + mq] = (_Float16)pe;
        ps += pe;
      }
      runl[r] += ps;
    }

    // V^T from registers -> LDS (prev readers drained at bar1)
#pragma unroll
    for (int u = 0; u < 4; ++u)
#pragma unroll
      for (int e2 = 0; e2 < 8; ++e2) Vs[(u * 4 + wave) * 8 + e2][lane] = vreg[u][e2];
    __syncthreads();   // bar2: Vs ready (Ps is wave-local)

    // O += P V
#pragma unroll
    for (int ks = 0; ks < 2; ++ks) {
      half8 ap = *(const half8*)&Ps[wm + mq][ks * 32 + quad * 8];
      half8 bf[8];
#pragma unroll
      for (int ct = 0; ct < 8; ++ct) bf[ct] = *(const half8*)&Vs[ct * 16 + mq][ks * 32 + quad * 8];
#pragma unroll
      for (int ct = 0; ct < 8; ++ct)
        acc_o[ct] = __builtin_amdgcn_mfma_f32_16x16x32_f16(ap, bf[ct], acc_o[ct], 0, 0, 0);
    }
  }

  // reduce per-lane partial denominators across mq (j-columns), once
#pragma unroll
  for (int r = 0; r < 4; ++r) {
    float l = runl[r];
    for (int off = 1; off < 16; off <<= 1) l += __shfl_xor(l, off, 64);
    runl[r] = l;
  }
  float inv[4];
#pragma unroll
  for (int r = 0; r < 4; ++r) inv[r] = (runl[r] > 0.f) ? 1.f / runl[r] : 0.f;
#pragma unroll
  for (int ct = 0; ct < 8; ++ct) {
    int d = ct * 16 + mq;
#pragma unroll
    for (int r = 0; r < 4; ++r) {
      int i = i0 + wm + quad * 4 + r;
      ctx[(size_t)i * 2048 + h * 128 + d] = (_Float16)(acc_o[ct][r] * inv[r]);
    }
  }
}

// ---------- launch ----------
extern "C" void kernel_launch(void* const* d_in, const int* in_sizes, int n_in,
                              void* d_out, int out_size, void* d_ws, size_t ws_size,
                              hipStream_t stream) {
  const float* hs   = (const float*)d_in[0];
  const float* cosb = (const float*)d_in[1];
  const float* sinb = (const float*)d_in[2];
  const float* Wq = (const float*)d_in[4];
  const float* bq = (const float*)d_in[5];
  const float* Wk = (const float*)d_in[6];
  const float* bk = (const float*)d_in[7];
  const float* Wv = (const float*)d_in[8];
  const float* bv = (const float*)d_in[9];
  const float* Wo = (const float*)d_in[10];
  float* out = (float*)d_out;

  char* ws = (char*)d_ws;
  // lifetimes:  WT(12M)@0 -> [ctxH(8M)@0 + stats@9M];  qkv(24M)@12M -> [WoT(8M)@12M + woP1(16M)@20M];
  //             hsH(8M)@36M -> kh+vh(4M)@36M;  qh(8M)@44M (biasqkv@44M dead before qh written);
  //             qkvP1(24M)@52M only if ws_size allows.
  _Float16* WT   = (_Float16*)ws;                       // [3072][2048] f16 12 MB @0
  _Float16* ctxH = (_Float16*)ws;                       // 8 MB @0 (after WT dead)
  float* rowmP   = (float*)(ws + (9u << 20));           // @9M (after WT dead): SPLIT x NH*SEQ
  float* rowlP   = rowmP + SPLIT * NH * SEQ;
  float* rowm    = rowlP + SPLIT * NH * SEQ;
  float* rowl    = rowm + NH * SEQ;
  float* colsumP = rowl + NH * SEQ;                     // SPLIT x NH*SEQ
  int*   hidx    = (int*)(colsumP + SPLIT * NH * SEQ);
  float* qkv     = (float*)(ws + (12u << 20));          // [2048][3072] f32 24 MB @12M
  _Float16* WoT  = (_Float16*)(ws + (12u << 20));       // 8 MB @12M (after qkv dead)
  float* woP1    = (float*)(ws + (20u << 20));          // 16 MB @20M (after qkv dead)
  _Float16* hsH  = (_Float16*)(ws + (36u << 20));       // 8 MB @36M
  _Float16* kh   = (_Float16*)(ws + (36u << 20));       // 2 MB @36M (after hsH dead)
  _Float16* vh   = (_Float16*)(ws + (38u << 20));       // 2 MB @38M
  _Float16* qh   = (_Float16*)(ws + (44u << 20));       // 8 MB @44M
  float* biasqkv = (float*)(ws + (44u << 20));          // 12 KB @44M (dead before qh written)
  bool splitqkv  = ws_size >= ((size_t)76 << 20);
  float* qkvP1   = (float*)(ws + (52u << 20));          // 24 MB @52M (only if splitqkv)

  cvt_h<<<(SEQ * 2048 / 4 + 255) / 256, 256, 0, stream>>>(hs, hsH, SEQ * 2048);
  transpose_qkv<<<dim3(2048 / 64, 2048 / 64, 3), 256, 0, stream>>>(Wq, Wk, Wv, WT);
  concat_bias<<<12, 256, 0, stream>>>(bq, bk, bv, biasqkv);

  // fused QKV projection: split-K=2 into separate f32 partials when workspace allows
  if (splitqkv)
    gemm_h<<<dim3(3072 / 128, 2048 / 128, 2), 256, 0, stream>>>(hsH, WT, biasqkv, qkv, qkvP1,
                                                                SEQ, 3072, 2048);
  else
    gemm_h<<<dim3(3072 / 128, 2048 / 128, 1), 256, 0, stream>>>(hsH, WT, biasqkv, qkv, nullptr,
                                                                SEQ, 3072, 2048);

  // RoPE + f16 emit (qh/kh/vh), summing partials; qkv and hsH dead afterwards
  int np = SEQ * 16 * 64 + SEQ * 4 * 64 + SEQ * 4 * 128;
  postproc<<<(np + 255) / 256, 256, 0, stream>>>(qkv, splitqkv ? qkvP1 : nullptr,
                                                 cosb, sinb, qh, kh, vh);

  // Wo transpose into qkv's (now dead) space
  transpose_h<<<dim3(2048 / 64, 2048 / 64), 256, 0, stream>>>(Wo, WoT, 2048, 2048);

  flashstats<<<dim3(SPLIT, SEQ / 128, NH), 256, 0, stream>>>(qh, kh, rowmP, rowlP);
  mergestats<<<(NH * SEQ + 255) / 256, 256, 0, stream>>>(rowmP, rowlP, rowm, rowl);
  flashcolsum<<<dim3(SPLIT, SEQ / 128, NH), 256, 0, stream>>>(qh, kh, rowm, rowl, colsumP);
  topk_radix<<<NH, 256, 0, stream>>>(colsumP, hidx);
  attn3<<<dim3(SEQ / 64, NH), 256, 0, stream>>>(qh, kh, vh, hidx, rowm, ctxH);

  // output projection: split-K=2, partial 0 straight into out, partial 1 added after
  gemm_h<<<dim3(2048 / 128, 2048 / 128, 2), 256, 0, stream>>>(ctxH, WoT, (const float*)nullptr,
                                                              out, woP1, SEQ, 2048, 2048);
  addout<<<(SEQ * 2048 / 4 + 255) / 256, 256, 0, stream>>>(out, woP1, SEQ * 2048);
}

// Round 5
// 370.815 us; speedup vs baseline: 1.2493x; 1.1051x over previous
//
#include <hip/hip_runtime.h>
#include <hip/hip_bf16.h>
#include <math.h>

constexpr int SEQ    = 2048;
constexpr int NH     = 16;
constexpr int HEAVY  = 204;   // int(0.1*2048)
constexpr int RECENT = 204;   // int(0.1*2048)
constexpr int SPLIT  = 4;     // flash stats/colsum split factor
constexpr float SCALE = 0.08838834764831845f; // 128^-0.5

typedef _Float16 half8 __attribute__((ext_vector_type(8)));
typedef float f32x4 __attribute__((ext_vector_type(4)));

typedef __attribute__((address_space(1))) const void cg_void;
typedef __attribute__((address_space(3))) void l_void;

// ---------- f32 -> f16 convert ----------
__global__ void cvt_h(const float* __restrict__ src, _Float16* __restrict__ dst, int n) {
  int i = (blockIdx.x * 256 + threadIdx.x) * 4;
  if (i + 3 < n) {
    float4 v = *(const float4*)(src + i);
    dst[i] = (_Float16)v.x; dst[i+1] = (_Float16)v.y;
    dst[i+2] = (_Float16)v.z; dst[i+3] = (_Float16)v.w;
  } else {
    for (int u = i; u < n; ++u) dst[u] = (_Float16)src[u];
  }
}

// ---------- transpose + convert: W f32 [K][N] -> WT f16 [N][K] ----------
__global__ __launch_bounds__(256) void transpose_h(
    const float* __restrict__ W, _Float16* __restrict__ WT, int K, int N) {
  __shared__ float T[64][65];
  int c = threadIdx.x & 63, rq = threadIdx.x >> 6;
  int n0 = blockIdx.x * 64, k0 = blockIdx.y * 64;
#pragma unroll
  for (int u = 0; u < 16; ++u) {
    int r = rq * 16 + u;
    T[r][c] = W[(size_t)(k0 + r) * N + n0 + c];
  }
  __syncthreads();
#pragma unroll
  for (int u = 0; u < 16; ++u) {
    int r = rq * 16 + u;
    WT[(size_t)(n0 + r) * K + k0 + c] = (_Float16)T[c][r];
  }
}

// ---------- batched transpose of Wq/Wk/Wv into WT ----------
__global__ __launch_bounds__(256) void transpose_qkv(
    const float* __restrict__ Wq, const float* __restrict__ Wk,
    const float* __restrict__ Wv, _Float16* __restrict__ WT) {
  int z = blockIdx.z;
  const float* W = (z == 0) ? Wq : ((z == 1) ? Wk : Wv);
  int N = (z == 0) ? 2048 : 512;
  size_t dstoff = (z == 0) ? 0 : ((z == 1) ? (size_t)2048 * 2048 : (size_t)2560 * 2048);
  int n0 = blockIdx.x * 64, k0 = blockIdx.y * 64;
  if (n0 >= N) return;
  __shared__ float T[64][65];
  int c = threadIdx.x & 63, rq = threadIdx.x >> 6;
#pragma unroll
  for (int u = 0; u < 16; ++u) {
    int r = rq * 16 + u;
    T[r][c] = W[(size_t)(k0 + r) * N + n0 + c];
  }
  __syncthreads();
#pragma unroll
  for (int u = 0; u < 16; ++u) {
    int r = rq * 16 + u;
    WT[dstoff + (size_t)(n0 + r) * 2048 + k0 + c] = (_Float16)T[c][r];
  }
}

// ---------- concat bias [bq|bk|bv] -> 3072 floats ----------
__global__ void concat_bias(const float* __restrict__ bq, const float* __restrict__ bk,
                            const float* __restrict__ bv, float* __restrict__ b) {
  int i = blockIdx.x * 256 + threadIdx.x;
  if (i < 2048) b[i] = bq[i];
  else if (i < 2560) b[i] = bk[i - 2048];
  else if (i < 3072) b[i] = bv[i - 2560];
}

// ---------- MFMA f16 GEMM, m97 structure, split-K via gridDim.z into SEPARATE buffers ----------
// LDS: linear [128][32] halfs, XOR-swizzled k-slots (pre-swizzled global src + swizzled read).
__global__ __launch_bounds__(256) void gemm_h(
    const _Float16* __restrict__ A, const _Float16* __restrict__ BT,
    const float* __restrict__ bias, float* __restrict__ C0, float* __restrict__ C1,
    int M, int N, int K)
{
  __shared__ _Float16 As[128 * 32];
  __shared__ _Float16 Bs[128 * 32];
  int tid = threadIdx.x, lane = tid & 63, wave = tid >> 6;
  int wm = (wave & 1) * 64, wn = (wave >> 1) * 64;
  int m0 = blockIdx.y * 128, n0 = blockIdx.x * 128;
  int mq = lane & 15, quad = lane >> 4;
  int kz = blockIdx.z, nz = gridDim.z;
  int kchunk = K / nz;
  int kbeg = kz * kchunk, kend = kbeg + kchunk;
  float* C = kz ? C1 : C0;

  f32x4 acc[4][4] = {};

  // staging: wave w covers rows [w*32, w*32+32), two 16-row segments of 1KB
  int rstage = wave * 32 + (lane >> 2);
  int qs = ((lane & 3) ^ ((lane >> 3) & 3)) * 8;   // pre-swizzled k-slot (halfs)
  const _Float16* gA = A  + (size_t)(m0 + rstage) * K + qs;
  const _Float16* gB = BT + (size_t)(n0 + rstage) * K + qs;
  _Float16* lA0 = &As[(wave * 32) * 32];
  _Float16* lA1 = &As[(wave * 32 + 16) * 32];
  _Float16* lB0 = &Bs[(wave * 32) * 32];
  _Float16* lB1 = &Bs[(wave * 32 + 16) * 32];

  int sw = (quad ^ ((mq >> 1) & 3)) * 8;           // read-side swizzled slot (halfs)

  for (int k0 = kbeg; k0 < kend; k0 += 32) {
    __builtin_amdgcn_global_load_lds((cg_void*)(gA + k0),                   (l_void*)lA0, 16, 0, 0);
    __builtin_amdgcn_global_load_lds((cg_void*)(gA + (size_t)16 * K + k0),  (l_void*)lA1, 16, 0, 0);
    __builtin_amdgcn_global_load_lds((cg_void*)(gB + k0),                   (l_void*)lB0, 16, 0, 0);
    __builtin_amdgcn_global_load_lds((cg_void*)(gB + (size_t)16 * K + k0),  (l_void*)lB1, 16, 0, 0);
    __syncthreads();
    half8 af[4], bf[4];
#pragma unroll
    for (int t4 = 0; t4 < 4; ++t4) {
      af[t4] = *(const half8*)&As[(wm + t4 * 16 + mq) * 32 + sw];
      bf[t4] = *(const half8*)&Bs[(wn + t4 * 16 + mq) * 32 + sw];
    }
#pragma unroll
    for (int mt = 0; mt < 4; ++mt)
#pragma unroll
      for (int nt = 0; nt < 4; ++nt)
        acc[mt][nt] = __builtin_amdgcn_mfma_f32_16x16x32_f16(af[mt], bf[nt], acc[mt][nt], 0, 0, 0);
    __syncthreads();
  }

#pragma unroll
  for (int mt = 0; mt < 4; ++mt)
#pragma unroll
    for (int nt = 0; nt < 4; ++nt) {
      int n = n0 + wn + nt * 16 + mq;
      float bb = (bias && kz == 0) ? bias[n] : 0.f;
#pragma unroll
      for (int r = 0; r < 4; ++r) {
        int m = m0 + wm + mt * 16 + quad * 4 + r;
        C[(size_t)m * N + n] = acc[mt][nt][r] + bb;
      }
    }
}

// ---------- add partial into out ----------
__global__ void addout(float* __restrict__ out, const float* __restrict__ p1, int n) {
  int i = (blockIdx.x * 256 + threadIdx.x) * 4;
  if (i + 3 < n) {
    float4 a = *(const float4*)(out + i);
    float4 b = *(const float4*)(p1 + i);
    a.x += b.x; a.y += b.y; a.z += b.z; a.w += b.w;
    *(float4*)(out + i) = a;
  } else {
    for (int u = i; u < n; ++u) out[u] += p1[u];
  }
}

// ---------- postproc: qkv partials f32 [s][3072] -> RoPE'd qh/kh + vh (all f16) ----------
__global__ void postproc(const float* __restrict__ qkv, const float* __restrict__ qkv1,
                         const float* __restrict__ cosb, const float* __restrict__ sinb,
                         _Float16* __restrict__ qh, _Float16* __restrict__ kh,
                         _Float16* __restrict__ vh) {
  int idx = blockIdx.x * 256 + threadIdx.x;
  const int NQ = SEQ * 16 * 64, NK = SEQ * 4 * 64, NV = SEQ * 4 * 128;
  bool sp = (qkv1 != nullptr);
  if (idx < NQ) {
    int d = idx & 63; int rest = idx >> 6; int h = rest & 15; int s = rest >> 4;
    size_t o = (size_t)s * 3072 + h * 128;
    float x1 = qkv[o + d]      + (sp ? qkv1[o + d] : 0.f);
    float x2 = qkv[o + d + 64] + (sp ? qkv1[o + d + 64] : 0.f);
    float c1 = cosb[(size_t)s * 128 + d], c2 = cosb[(size_t)s * 128 + d + 64];
    float s1 = sinb[(size_t)s * 128 + d], s2 = sinb[(size_t)s * 128 + d + 64];
    qh[(size_t)s * 2048 + h * 128 + d]      = (_Float16)(x1 * c1 - x2 * s1);
    qh[(size_t)s * 2048 + h * 128 + d + 64] = (_Float16)(x2 * c2 + x1 * s2);
  } else if (idx < NQ + NK) {
    int r = idx - NQ;
    int d = r & 63; int rest = r >> 6; int h = rest & 3; int s = rest >> 2;
    size_t o = (size_t)s * 3072 + 2048 + h * 128;
    float x1 = qkv[o + d]      + (sp ? qkv1[o + d] : 0.f);
    float x2 = qkv[o + d + 64] + (sp ? qkv1[o + d + 64] : 0.f);
    float c1 = cosb[(size_t)s * 128 + d], c2 = cosb[(size_t)s * 128 + d + 64];
    float s1 = sinb[(size_t)s * 128 + d], s2 = sinb[(size_t)s * 128 + d + 64];
    kh[(size_t)s * 512 + h * 128 + d]      = (_Float16)(x1 * c1 - x2 * s1);
    kh[(size_t)s * 512 + h * 128 + d + 64] = (_Float16)(x2 * c2 + x1 * s2);
  } else if (idx < NQ + NK + NV) {
    int r = idx - NQ - NK;
    int d = r & 127; int rest = r >> 7; int h = rest & 3; int s = rest >> 2;
    size_t o = (size_t)s * 3072 + 2560 + h * 128 + d;
    float x = qkv[o] + (sp ? qkv1[o] : 0.f);
    vh[(size_t)s * 512 + h * 128 + d] = (_Float16)x;
  }
}

// ---------- S1: flash row stats (m_i, l_i), Q in registers, per-lane online, j-split ----------
__global__ __launch_bounds__(256) void flashstats(
    const _Float16* __restrict__ qh, const _Float16* __restrict__ kh,
    float* __restrict__ rowmP, float* __restrict__ rowlP)
{
  int sp = blockIdx.x;                    // j-split 0..SPLIT-1
  int ib = blockIdx.y;
  int i0 = ib * 128, h = blockIdx.z, kvh = h >> 2;
  __shared__ _Float16 Ks[128][136];
  int tid = threadIdx.x, lane = tid & 63, wave = tid >> 6;
  int mq = lane & 15, quad = lane >> 4;
  int wm = wave * 32;

  // Q fragments held in registers (per-lane MFMA A-fragment, loaded once)
  half8 aq[2][4];
#pragma unroll
  for (int rt = 0; rt < 2; ++rt)
#pragma unroll
    for (int ks = 0; ks < 4; ++ks)
      aq[rt][ks] = *(const half8*)(qh + (size_t)(i0 + wm + rt * 16 + mq) * 2048 + h * 128 + ks * 32 + quad * 8);

  // per-LANE running stats over this lane's j-columns only; merged across mq at the end
  float runm[2][4], runl[2][4];
#pragma unroll
  for (int rt = 0; rt < 2; ++rt)
#pragma unroll
    for (int r = 0; r < 4; ++r) { runm[rt][r] = -INFINITY; runl[rt][r] = 0.f; }

  int nblk = ib + 1;
  int jb_lo = (sp * nblk) / SPLIT;
  int jb_hi = ((sp + 1) * nblk) / SPLIT;
  for (int jb = jb_lo; jb < jb_hi; ++jb) {
    int j0 = jb * 128;
    __syncthreads();
#pragma unroll
    for (int u = 0; u < 8; ++u) {
      int unit = u * 256 + tid;
      int r = unit >> 4, c8 = (unit & 15) * 8;
      *(half8*)&Ks[r][c8] = *(const half8*)(kh + (size_t)(j0 + r) * 512 + kvh * 128 + c8);
    }
    __syncthreads();

    f32x4 acc[2][8] = {};
#pragma unroll
    for (int ks = 0; ks < 4; ++ks) {
      half8 bf[8];
#pragma unroll
      for (int ct = 0; ct < 8; ++ct) bf[ct] = *(const half8*)&Ks[ct * 16 + mq][ks * 32 + quad * 8];
#pragma unroll
      for (int rt = 0; rt < 2; ++rt)
#pragma unroll
        for (int ct = 0; ct < 8; ++ct)
          acc[rt][ct] = __builtin_amdgcn_mfma_f32_16x16x32_f16(aq[rt][ks], bf[ct], acc[rt][ct], 0, 0, 0);
    }

#pragma unroll
    for (int rt = 0; rt < 2; ++rt) {
      int rbase = i0 + wm + rt * 16 + quad * 4;
#pragma unroll
      for (int ct = 0; ct < 8; ++ct) {
        int j = j0 + ct * 16 + mq;
#pragma unroll
        for (int r = 0; r < 4; ++r) {
          float s = acc[rt][ct][r] * SCALE;
          if (j > rbase + r) s = -INFINITY;
          acc[rt][ct][r] = s;
        }
      }
#pragma unroll
      for (int r = 0; r < 4; ++r) {
        float v = acc[rt][0][r];
#pragma unroll
        for (int ct = 1; ct < 8; ++ct) v = fmaxf(v, acc[rt][ct][r]);
        float nm = fmaxf(runm[rt][r], v);
        float sn = (nm == -INFINITY) ? 0.f : nm;
        float alpha = (runm[rt][r] == -INFINITY) ? 0.f : __expf(runm[rt][r] - nm);
        float ps = 0.f;
#pragma unroll
        for (int ct = 0; ct < 8; ++ct) {
          float x = acc[rt][ct][r];
          ps += (x == -INFINITY) ? 0.f : __expf(x - sn);
        }
        runl[rt][r] = runl[rt][r] * alpha + ps;
        runm[rt][r] = nm;
      }
    }
  }

  // cross-lane (mq) merge of (m,l), once
#pragma unroll
  for (int rt = 0; rt < 2; ++rt)
#pragma unroll
    for (int r = 0; r < 4; ++r) {
      float m = runm[rt][r], l = runl[rt][r];
      for (int off = 1; off < 16; off <<= 1) {
        float om = __shfl_xor(m, off, 64);
        float ol = __shfl_xor(l, off, 64);
        float nm = fmaxf(m, om);
        float a = (m  == -INFINITY) ? 0.f : __expf(m - nm);
        float b = (om == -INFINITY) ? 0.f : __expf(om - nm);
        l = l * a + ol * b;
        m = nm;
      }
      runm[rt][r] = m; runl[rt][r] = l;
    }

  if (mq == 0) {
#pragma unroll
    for (int rt = 0; rt < 2; ++rt)
#pragma unroll
      for (int r = 0; r < 4; ++r) {
        int i = i0 + wm + rt * 16 + quad * 4 + r;
        rowmP[sp * (NH * SEQ) + h * SEQ + i] = runm[rt][r];
        rowlP[sp * (NH * SEQ) + h * SEQ + i] = runl[rt][r];
      }
  }
}

// ---------- merge split row stats ----------
__global__ void mergestats(const float* __restrict__ rowmP, const float* __restrict__ rowlP,
                           float* __restrict__ rowm, float* __restrict__ rowl) {
  int i = blockIdx.x * 256 + threadIdx.x;
  if (i >= NH * SEQ) return;
  float m = -INFINITY;
#pragma unroll
  for (int s = 0; s < SPLIT; ++s) m = fmaxf(m, rowmP[s * (NH * SEQ) + i]);
  float l = 0.f;
#pragma unroll
  for (int s = 0; s < SPLIT; ++s) {
    float ls = rowlP[s * (NH * SEQ) + i];
    if (ls > 0.f) l += ls * __expf(rowmP[s * (NH * SEQ) + i] - m);
  }
  rowm[i] = m; rowl[i] = l;
}

// ---------- S2: colsum[h][j] = sum_i exp(s_ij - m_i)/l_i, Q streamed, i-split ----------
__global__ __launch_bounds__(256) void flashcolsum(
    const _Float16* __restrict__ qh, const _Float16* __restrict__ kh,
    const float* __restrict__ rowm, const float* __restrict__ rowl,
    float* __restrict__ colsumP)
{
  int sp = blockIdx.x;                    // i-split 0..SPLIT-1
  int jb = blockIdx.y;
  int j0 = jb * 128, h = blockIdx.z, kvh = h >> 2;
  __shared__ _Float16 Ks[128][136];
  __shared__ float colred[4][128];
  int tid = threadIdx.x, lane = tid & 63, wave = tid >> 6;
  int mq = lane & 15, quad = lane >> 4;
  int wm = wave * 32;

#pragma unroll
  for (int u = 0; u < 8; ++u) {
    int unit = u * 256 + tid;
    int r = unit >> 4, c8 = (unit & 15) * 8;
    *(half8*)&Ks[r][c8] = *(const half8*)(kh + (size_t)(j0 + r) * 512 + kvh * 128 + c8);
  }
  __syncthreads();

  float colacc[8] = {};
  int n = SEQ / 128 - jb;
  int ib_lo = jb + (sp * n) / SPLIT;
  int ib_hi = jb + ((sp + 1) * n) / SPLIT;
  for (int ib = ib_lo; ib < ib_hi; ++ib) {
    int i0 = ib * 128;

    f32x4 acc[2][8] = {};
#pragma unroll
    for (int ks = 0; ks < 4; ++ks) {
      half8 af[2], bf[8];
#pragma unroll
      for (int rt = 0; rt < 2; ++rt)
        af[rt] = *(const half8*)(qh + (size_t)(i0 + wm + rt * 16 + mq) * 2048 + h * 128 + ks * 32 + quad * 8);
#pragma unroll
      for (int ct = 0; ct < 8; ++ct) bf[ct] = *(const half8*)&Ks[ct * 16 + mq][ks * 32 + quad * 8];
#pragma unroll
      for (int rt = 0; rt < 2; ++rt)
#pragma unroll
        for (int ct = 0; ct < 8; ++ct)
          acc[rt][ct] = __builtin_amdgcn_mfma_f32_16x16x32_f16(af[rt], bf[ct], acc[rt][ct], 0, 0, 0);
    }

#pragma unroll
    for (int rt = 0; rt < 2; ++rt) {
      int rbase = i0 + wm + rt * 16 + quad * 4;
      float rm[4], ri[4];
#pragma unroll
      for (int r = 0; r < 4; ++r) {
        rm[r] = rowm[h * SEQ + rbase + r];
        ri[r] = 1.f / rowl[h * SEQ + rbase + r];
      }
#pragma unroll
      for (int ct = 0; ct < 8; ++ct) {
        int j = j0 + ct * 16 + mq;
        float cp = 0.f;
#pragma unroll
        for (int r = 0; r < 4; ++r) {
          if (j <= rbase + r)
            cp += __expf(acc[rt][ct][r] * SCALE - rm[r]) * ri[r];
        }
        colacc[ct] += cp;
      }
    }
  }
#pragma unroll
  for (int ct = 0; ct < 8; ++ct) {
    float v = colacc[ct];
    v += __shfl_xor(v, 16, 64);
    v += __shfl_xor(v, 32, 64);
    colacc[ct] = v;
  }
  __syncthreads();
  if (quad == 0) {
#pragma unroll
    for (int ct = 0; ct < 8; ++ct) colred[wave][ct * 16 + mq] = colacc[ct];
  }
  __syncthreads();
  if (tid < 128)
    colsumP[sp * (NH * SEQ) + h * SEQ + j0 + tid] =
        colred[0][tid] + colred[1][tid] + colred[2][tid] + colred[3][tid];
}

// ---------- top-HEAVY per head via radix select, parallel suffix-scan bucket pick ----------
__global__ __launch_bounds__(256) void topk_radix(const float* __restrict__ colsumP,
                                                  int* __restrict__ hidx) {
  int h = blockIdx.x, t = threadIdx.x;
  __shared__ unsigned vals[SEQ];
  __shared__ int hist[256];
  __shared__ int scanbuf[256];
  __shared__ unsigned s_prefix;
  __shared__ int s_k;

  for (int j = t; j < SEQ; j += 256) {
    float cs = 0.f;
#pragma unroll
    for (int s = 0; s < SPLIT; ++s) cs += colsumP[s * (NH * SEQ) + h * SEQ + j];
    vals[j] = __float_as_uint(cs);
  }

  unsigned prefix = 0, maskFixed = 0;
  int k = HEAVY;
  for (int pass = 0; pass < 4; ++pass) {
    int shift = 24 - pass * 8;
    hist[t] = 0;
    __syncthreads();
    for (int j = t; j < SEQ; j += 256) {
      unsigned v = vals[j];
      if ((v & maskFixed) == prefix) atomicAdd(&hist[(v >> shift) & 255], 1);
    }
    __syncthreads();
    // parallel suffix-sum S[t] = sum_{e>=t} hist[e]  (Hillis-Steele, 8 steps)
    scanbuf[t] = hist[t];
    __syncthreads();
    for (int off = 1; off < 256; off <<= 1) {
      int x = (t + off < 256) ? scanbuf[t + off] : 0;
      __syncthreads();
      scanbuf[t] += x;
      __syncthreads();
    }
    // unique bucket with S[t] >= k > S[t+1] (S non-increasing; S[0] >= k invariant)
    int S = scanbuf[t];
    int Snext = (t < 255) ? scanbuf[t + 1] : 0;
    if (S >= k && Snext < k) {
      s_prefix = prefix | ((unsigned)t << shift);
      s_k = k - (S - hist[t]);     // k minus count strictly above this bucket
    }
    __syncthreads();
    prefix = s_prefix;
    k = s_k;
    maskFixed |= (0xFFu << shift);
    __syncthreads();
  }
  unsigned T = prefix;
  int tieNeed = k;

  int base = t * 8;
  int cG = 0, cT = 0;
#pragma unroll
  for (int u = 0; u < 8; ++u) {
    unsigned v = vals[base + u];
    if (v > T) cG++;
    else if (v == T) cT++;
  }
  scanbuf[t] = cG; __syncthreads();
  for (int off = 1; off < 256; off <<= 1) {
    int x = (t >= off) ? scanbuf[t - off] : 0;
    __syncthreads();
    scanbuf[t] += x;
    __syncthreads();
  }
  int exG = scanbuf[t] - cG;
  int totG = scanbuf[255];
  __syncthreads();
  scanbuf[t] = cT; __syncthreads();
  for (int off = 1; off < 256; off <<= 1) {
    int x = (t >= off) ? scanbuf[t - off] : 0;
    __syncthreads();
    scanbuf[t] += x;
    __syncthreads();
  }
  int exT = scanbuf[t] - cT;

  int slotG = exG;
  int slotT = totG + exT;
#pragma unroll
  for (int u = 0; u < 8; ++u) {
    unsigned v = vals[base + u];
    if (v > T) {
      hidx[h * HEAVY + slotG] = base + u;
      slotG++;
    } else if (v == T) {
      if (slotT < totG + tieNeed) hidx[h * HEAVY + slotT] = base + u;
      slotT++;
    }
  }
}

// ---------- attn3: sparse flash attention, NO online softmax ----------
// Uses precomputed full-causal row max (rowm) as the exp reference point:
// an upper bound on the masked-subset max, so P = exp(s - rowm) in (0,1],
// numerator and denominator scale identically -> O unchanged, but no
// cross-lane max, no alpha rescale, no in-loop shfl.  V is loaded to
// registers at tile start (latency hides under QK^T), 2 barriers/tile.
__global__ __launch_bounds__(256) void attn3(
    const _Float16* __restrict__ qh, const _Float16* __restrict__ kh,
    const _Float16* __restrict__ vh, const int* __restrict__ hidx,
    const float* __restrict__ rowm, _Float16* __restrict__ ctx)
{
  constexpr int TB = 64;
  int i0 = blockIdx.x * 64, h = blockIdx.y, kvh = h >> 2;
  __shared__ _Float16 Ks[64][136];        // K tile
  __shared__ _Float16 Vs[128][72];        // V^T tile
  __shared__ _Float16 Ps[64][72];         // P tile (wave-local rows)
  __shared__ int shx[HEAVY];
  int tid = threadIdx.x, lane = tid & 63, wave = tid >> 6;
  int mq = lane & 15, quad = lane >> 4;
  int wm = wave * 16;

  for (int e = tid; e < HEAVY; e += 256) shx[e] = hidx[h * HEAVY + e];

  // Q fragment + row-max reference, straight from global (per-lane)
  half8 aq[4];
#pragma unroll
  for (int ks = 0; ks < 4; ++ks)
    aq[ks] = *(const half8*)(qh + (size_t)(i0 + wm + mq) * 2048 + h * 128 + ks * 32 + quad * 8);
  float rm[4];
#pragma unroll
  for (int r = 0; r < 4; ++r) rm[r] = rowm[h * SEQ + i0 + wm + quad * 4 + r];

  float runl[4] = {0.f, 0.f, 0.f, 0.f};
  f32x4 acc_o[8] = {};
  __syncthreads();   // shx ready

  int tb_lo = max(0, i0 - RECENT) >> 6;
  int tb_hi = (i0 + 63) >> 6;
  int nband = tb_hi - tb_lo + 1;
  int nheavy = (i0 + 63 > RECENT) ? ((HEAVY + TB - 1) / TB) : 0;
  int ntiles = nband + nheavy;

  for (int tt = 0; tt < ntiles; ++tt) {
    bool isheavy = tt >= nband;
    int j0 = isheavy ? 0 : (tb_lo + tt) * TB;
    int e0 = isheavy ? (tt - nband) * TB : 0;

    // V tile -> registers (each thread: column (e0|j0)+lane, dim octets (u*4+wave)*8)
    int jv;
    if (!isheavy) jv = j0 + lane;
    else { int e = e0 + lane; jv = (e < HEAVY) ? shx[e] : 0; }
    half8 vreg[4];
#pragma unroll
    for (int u = 0; u < 4; ++u)
      vreg[u] = *(const half8*)(vh + (size_t)jv * 512 + kvh * 128 + (u * 4 + wave) * 8);

    // K tile -> LDS (64 cols x 128 dims): 16 lanes per row, 256B contiguous
#pragma unroll
    for (int u = 0; u < 4; ++u) {
      int unit = u * 256 + tid;
      int c = unit >> 4, d8 = (unit & 15) * 8;
      int jabs;
      if (!isheavy) jabs = j0 + c;
      else { int e = e0 + c; jabs = (e < HEAVY) ? shx[e] : 0; }
      *(half8*)&Ks[c][d8] = *(const half8*)(kh + (size_t)jabs * 512 + kvh * 128 + d8);
    }
    int jreg[4];
#pragma unroll
    for (int ct = 0; ct < 4; ++ct) {
      int c = ct * 16 + mq;
      if (!isheavy) jreg[ct] = j0 + c;
      else { int e = e0 + c; jreg[ct] = (e < HEAVY) ? shx[e] : (1 << 28); }
    }
    __syncthreads();   // bar1: Ks ready; prev-tile Vs reads all complete

    // S = Q K^T
    f32x4 s[4] = {};
#pragma unroll
    for (int ks = 0; ks < 4; ++ks) {
      half8 bf[4];
#pragma unroll
      for (int ct = 0; ct < 4; ++ct) bf[ct] = *(const half8*)&Ks[ct * 16 + mq][ks * 32 + quad * 8];
#pragma unroll
      for (int ct = 0; ct < 4; ++ct)
        s[ct] = __builtin_amdgcn_mfma_f32_16x16x32_f16(aq[ks], bf[ct], s[ct], 0, 0, 0);
    }

    // mask + exp against precomputed row max; per-lane partial denominator
#pragma unroll
    for (int r = 0; r < 4; ++r) {
      int i = i0 + wm + quad * 4 + r;
      float ps = 0.f;
#pragma unroll
      for (int ct = 0; ct < 4; ++ct) {
        int j = jreg[ct];
        bool ok = isheavy ? (j < i - RECENT) : (j >= i - RECENT && j <= i);
        float pe = ok ? __expf(s[ct][r] * SCALE - rm[r]) : 0.f;
        Ps[wm + quad * 4 + r][ct * 16 + mq] = (_Float16)pe;
        ps += pe;
      }
      runl[r] += ps;
    }

    // V^T from registers -> LDS (prev readers drained at bar1)
#pragma unroll
    for (int u = 0; u < 4; ++u)
#pragma unroll
      for (int e2 = 0; e2 < 8; ++e2) Vs[(u * 4 + wave) * 8 + e2][lane] = vreg[u][e2];
    __syncthreads();   // bar2: Vs ready (Ps is wave-local)

    // O += P V
#pragma unroll
    for (int ks = 0; ks < 2; ++ks) {
      half8 ap = *(const half8*)&Ps[wm + mq][ks * 32 + quad * 8];
      half8 bf[8];
#pragma unroll
      for (int ct = 0; ct < 8; ++ct) bf[ct] = *(const half8*)&Vs[ct * 16 + mq][ks * 32 + quad * 8];
#pragma unroll
      for (int ct = 0; ct < 8; ++ct)
        acc_o[ct] = __builtin_amdgcn_mfma_f32_16x16x32_f16(ap, bf[ct], acc_o[ct], 0, 0, 0);
    }
  }

  // reduce per-lane partial denominators across mq (j-columns), once
#pragma unroll
  for (int r = 0; r < 4; ++r) {
    float l = runl[r];
    for (int off = 1; off < 16; off <<= 1) l += __shfl_xor(l, off, 64);
    runl[r] = l;
  }
  float inv[4];
#pragma unroll
  for (int r = 0; r < 4; ++r) inv[r] = (runl[r] > 0.f) ? 1.f / runl[r] : 0.f;
#pragma unroll
  for (int ct = 0; ct < 8; ++ct) {
    int d = ct * 16 + mq;
#pragma unroll
    for (int r = 0; r < 4; ++r) {
      int i = i0 + wm + quad * 4 + r;
      ctx[(size_t)i * 2048 + h * 128 + d] = (_Float16)(acc_o[ct][r] * inv[r]);
    }
  }
}

// ---------- launch ----------
extern "C" void kernel_launch(void* const* d_in, const int* in_sizes, int n_in,
                              void* d_out, int out_size, void* d_ws, size_t ws_size,
                              hipStream_t stream) {
  const float* hs   = (const float*)d_in[0];
  const float* cosb = (const float*)d_in[1];
  const float* sinb = (const float*)d_in[2];
  const float* Wq = (const float*)d_in[4];
  const float* bq = (const float*)d_in[5];
  const float* Wk = (const float*)d_in[6];
  const float* bk = (const float*)d_in[7];
  const float* Wv = (const float*)d_in[8];
  const float* bv = (const float*)d_in[9];
  const float* Wo = (const float*)d_in[10];
  float* out = (float*)d_out;

  char* ws = (char*)d_ws;
  // lifetimes:  WT(12M)@0 -> [ctxH(8M)@0 + stats@9M];  qkv(24M)@12M -> [WoT(8M)@12M + woP1(16M)@20M];
  //             hsH(8M)@36M -> kh+vh(4M)@36M;  qh(8M)@44M (biasqkv@44M dead before qh written);
  //             qkvP1(24M)@52M only if ws_size allows.
  _Float16* WT   = (_Float16*)ws;                       // [3072][2048] f16 12 MB @0
  _Float16* ctxH = (_Float16*)ws;                       // 8 MB @0 (after WT dead)
  float* rowmP   = (float*)(ws + (9u << 20));           // @9M (after WT dead): SPLIT x NH*SEQ
  float* rowlP   = rowmP + SPLIT * NH * SEQ;
  float* rowm    = rowlP + SPLIT * NH * SEQ;
  float* rowl    = rowm + NH * SEQ;
  float* colsumP = rowl + NH * SEQ;                     // SPLIT x NH*SEQ
  int*   hidx    = (int*)(colsumP + SPLIT * NH * SEQ);
  float* qkv     = (float*)(ws + (12u << 20));          // [2048][3072] f32 24 MB @12M
  _Float16* WoT  = (_Float16*)(ws + (12u << 20));       // 8 MB @12M (after qkv dead)
  float* woP1    = (float*)(ws + (20u << 20));          // 16 MB @20M (after qkv dead)
  _Float16* hsH  = (_Float16*)(ws + (36u << 20));       // 8 MB @36M
  _Float16* kh   = (_Float16*)(ws + (36u << 20));       // 2 MB @36M (after hsH dead)
  _Float16* vh   = (_Float16*)(ws + (38u << 20));       // 2 MB @38M
  _Float16* qh   = (_Float16*)(ws + (44u << 20));       // 8 MB @44M
  float* biasqkv = (float*)(ws + (44u << 20));          // 12 KB @44M (dead before qh written)
  bool splitqkv  = ws_size >= ((size_t)76 << 20);
  float* qkvP1   = (float*)(ws + (52u << 20));          // 24 MB @52M (only if splitqkv)

  cvt_h<<<(SEQ * 2048 / 4 + 255) / 256, 256, 0, stream>>>(hs, hsH, SEQ * 2048);
  transpose_qkv<<<dim3(2048 / 64, 2048 / 64, 3), 256, 0, stream>>>(Wq, Wk, Wv, WT);
  concat_bias<<<12, 256, 0, stream>>>(bq, bk, bv, biasqkv);

  // fused QKV projection: split-K=2 into separate f32 partials when workspace allows
  if (splitqkv)
    gemm_h<<<dim3(3072 / 128, 2048 / 128, 2), 256, 0, stream>>>(hsH, WT, biasqkv, qkv, qkvP1,
                                                                SEQ, 3072, 2048);
  else
    gemm_h<<<dim3(3072 / 128, 2048 / 128, 1), 256, 0, stream>>>(hsH, WT, biasqkv, qkv, nullptr,
                                                                SEQ, 3072, 2048);

  // RoPE + f16 emit (qh/kh/vh), summing partials; qkv and hsH dead afterwards
  int np = SEQ * 16 * 64 + SEQ * 4 * 64 + SEQ * 4 * 128;
  postproc<<<(np + 255) / 256, 256, 0, stream>>>(qkv, splitqkv ? qkvP1 : nullptr,
                                                 cosb, sinb, qh, kh, vh);

  // Wo transpose into qkv's (now dead) space
  transpose_h<<<dim3(2048 / 64, 2048 / 64), 256, 0, stream>>>(Wo, WoT, 2048, 2048);

  flashstats<<<dim3(SPLIT, SEQ / 128, NH), 256, 0, stream>>>(qh, kh, rowmP, rowlP);
  mergestats<<<(NH * SEQ + 255) / 256, 256, 0, stream>>>(rowmP, rowlP, rowm, rowl);
  flashcolsum<<<dim3(SPLIT, SEQ / 128, NH), 256, 0, stream>>>(qh, kh, rowm, rowl, colsumP);
  topk_radix<<<NH, 256, 0, stream>>>(colsumP, hidx);
  attn3<<<dim3(SEQ / 64, NH), 256, 0, stream>>>(qh, kh, vh, hidx, rowm, ctxH);

  // output projection: split-K=2, partial 0 straight into out, partial 1 added after
  gemm_h<<<dim3(2048 / 128, 2048 / 128, 2), 256, 0, stream>>>(ctxH, WoT, (const float*)nullptr,
                                                              out, woP1, SEQ, 2048, 2048);
  addout<<<(SEQ * 2048 / 4 + 255) / 256, 256, 0, stream>>>(out, woP1, SEQ * 2048);
}